// Round 1
// baseline (747.073 us; speedup 1.0000x reference)
//
#include <hip/hip_runtime.h>

#define BB 8
#define NN 2048
#define DP 64
#define DM 512
#define KNNK 16
#define ROWS (BB*NN)   // 16384

typedef __attribute__((ext_vector_type(8))) short s16x8;
typedef __attribute__((ext_vector_type(4))) short s16x4;
typedef __attribute__((ext_vector_type(4))) float f32x4;

__device__ __forceinline__ float bf2f(short u){
  union { unsigned int i; float f; } v; v.i = ((unsigned int)(unsigned short)u) << 16; return v.f;
}
__device__ __forceinline__ short f2bf(float f){
  union { float f; unsigned int i; } v; v.f = f;
  unsigned int x = v.i;
  return (short)((x + 0x7fffu + ((x >> 16) & 1u)) >> 16);
}

// ---------------- sq = ||xyz||^2 ----------------
__global__ void k_sq(const float* __restrict__ xyz, float* __restrict__ sq){
  int i = blockIdx.x*256 + threadIdx.x;
  if (i < ROWS){
    float x = xyz[3*i], y = xyz[3*i+1], z = xyz[3*i+2];
    sq[i] = x*x + y*y + z*z;
  }
}

// ---------------- exact knn: iterative argmin over LDS dists ----------------
__global__ __launch_bounds__(256) void k_knn(const float* __restrict__ xyz, const float* __restrict__ sq,
        int* __restrict__ kidx, float* __restrict__ kw, float* __restrict__ wsum){
  int row = blockIdx.x;
  int b = row >> 11; int i = row & (NN-1);
  const float* xb = xyz + (size_t)b*NN*3;
  const float* sqb = sq + (size_t)b*NN;
  int t = threadIdx.x;
  __shared__ float dloc[NN];
  __shared__ float rv[256];
  __shared__ int   ri[256];
  float xi0 = xb[3*i], xi1 = xb[3*i+1], xi2 = xb[3*i+2];
  float sqi = sqb[i];
  for (int j = t; j < NN; j += 256){
    float d = sqi + sqb[j] - 2.0f*(xi0*xb[3*j] + xi1*xb[3*j+1] + xi2*xb[3*j+2]);
    dloc[j] = d;
  }
  __syncthreads();
  float wacc = 0.f;
  for (int sel = 0; sel < KNNK; ++sel){
    float best = 3.0e38f; int bi = NN;
    for (int j = t; j < NN; j += 256){
      float d = dloc[j];
      if (d < best){ best = d; bi = j; }
    }
    rv[t] = best; ri[t] = bi;
    __syncthreads();
    for (int s = 128; s > 0; s >>= 1){
      if (t < s){
        float ov = rv[t+s]; int oi = ri[t+s];
        if (ov < rv[t] || (ov == rv[t] && oi < ri[t])){ rv[t]=ov; ri[t]=oi; }
      }
      __syncthreads();
    }
    if (t == 0){
      int j = ri[0]; float d = rv[0];
      dloc[j] = 3.0e38f;
      kidx[(size_t)row*KNNK + sel] = j;
      float w = 1.0f/(d + 1e-6f);
      kw[(size_t)row*KNNK + sel] = w;
      wacc += w;
    }
    __syncthreads();
  }
  if (t == 0) wsum[row] = wacc;
}

// ---------------- convert+transpose the 512x512 weights to bf16 [n][k] ----------------
__global__ void k_prep(const float* __restrict__ Wq, const float* __restrict__ Wk,
                       const float* __restrict__ Wv, const float* __restrict__ Wd2,
                       short* __restrict__ Wqt, short* __restrict__ Wkt,
                       short* __restrict__ Wvt, short* __restrict__ Wd2t){
  int idx = blockIdx.x*256 + threadIdx.x;   // 4*512*512
  int m = idx / (DM*DM); int r = idx % (DM*DM);
  int n = r / DM; int k = r % DM;
  const float* W = (m==0)?Wq:(m==1)?Wk:(m==2)?Wv:Wd2;
  short* Wt = (m==0)?Wqt:(m==1)?Wkt:(m==2)?Wvt:Wd2t;
  Wt[r] = f2bf(W[(size_t)k*DM + n]);
}

// ---------------- Prelu[row][d] = relu(xyz@Wd1 + bd1), bf16 ----------------
__global__ void k_prelu(const float* __restrict__ xyz, const float* __restrict__ Wd1,
                        const float* __restrict__ bd1, short* __restrict__ Prelu){
  int idx = blockIdx.x*256 + threadIdx.x;   // ROWS*DM
  int row = idx >> 9; int d = idx & (DM-1);
  float x0 = xyz[3*row], x1 = xyz[3*row+1], x2 = xyz[3*row+2];
  float v = x0*Wd1[d] + x1*Wd1[DM + d] + x2*Wd1[2*DM + d] + bd1[d];
  Prelu[idx] = f2bf(fmaxf(v, 0.f));
}

// ---------------- x = features@W1 + b1 (f32 compute, bf16 out), 4 rows/block ----------------
__global__ __launch_bounds__(256) void k_fc1(const float* __restrict__ feat, const float* __restrict__ W1,
                       const float* __restrict__ b1, short* __restrict__ x){
  int r0 = blockIdx.x*4;
  __shared__ float f[4][DP];
  int t = threadIdx.x;
  if (t < 4*DP) f[t>>6][t&63] = feat[(size_t)r0*DP + t];
  __syncthreads();
  for (int c = t; c < DM; c += 256){
    float bb = b1[c];
    float a0=bb,a1=bb,a2=bb,a3=bb;
    #pragma unroll 8
    for (int k = 0; k < DP; ++k){
      float w = W1[(size_t)k*DM + c];
      a0 += f[0][k]*w; a1 += f[1][k]*w; a2 += f[2][k]*w; a3 += f[3][k]*w;
    }
    x[(size_t)(r0+0)*DM + c] = f2bf(a0);
    x[(size_t)(r0+1)*DM + c] = f2bf(a1);
    x[(size_t)(r0+2)*DM + c] = f2bf(a2);
    x[(size_t)(r0+3)*DM + c] = f2bf(a3);
  }
}

// ---------------- g = (sum_j w_j * Prelu[idx_j]) / wsum, bf16 ----------------
__global__ __launch_bounds__(256) void k_g(const short* __restrict__ Prelu, const int* __restrict__ kidx,
                   const float* __restrict__ kw, const float* __restrict__ wsum, short* __restrict__ g){
  int row = blockIdx.x;
  int b = row >> 11;
  int t = threadIdx.x;
  __shared__ int sidx[KNNK]; __shared__ float sw[KNNK];
  if (t < KNNK){ sidx[t] = kidx[(size_t)row*KNNK + t]; sw[t] = kw[(size_t)row*KNNK + t]; }
  __syncthreads();
  float inv = 1.0f / wsum[row];
  float a0 = 0.f, a1 = 0.f;
  const short* Pb = Prelu + (size_t)b*NN*DM;
  #pragma unroll
  for (int j = 0; j < KNNK; ++j){
    const short* pr = Pb + (size_t)sidx[j]*DM;
    float wj = sw[j];
    a0 += wj*bf2f(pr[t]);
    a1 += wj*bf2f(pr[t+256]);
  }
  g[(size_t)row*DM + t]       = f2bf(a0*inv);
  g[(size_t)row*DM + t + 256] = f2bf(a1*inv);
}

// ---------------- bf16 MFMA GEMM: C[M,512] = A[M,512] @ Bt[n][k]^T ----------------
// mode 0: outf[row*DM+col] = acc + bias[col]            (f32, for wa)
// mode 1: outb[row*DM+col] = bf16(acc + addf[row*DM+col]) (qe/ke/ve)
__global__ __launch_bounds__(256) void k_gemm(const short* __restrict__ A, const short* __restrict__ Bt,
       const float* __restrict__ bias, const float* __restrict__ addf,
       float* __restrict__ outf, short* __restrict__ outb, int mode){
  __shared__ short As[64][40];
  __shared__ short Bs[64][40];
  int t = threadIdx.x;
  int i0 = blockIdx.x*64;
  int n0 = blockIdx.y*64;
  int w = t >> 6; int l = t & 63;
  int wr = w >> 1, wc = w & 1;
  f32x4 acc[2][2];
  #pragma unroll
  for (int h=0;h<2;++h)
    #pragma unroll
    for (int c=0;c<2;++c) acc[h][c] = (f32x4){0.f,0.f,0.f,0.f};
  int lrow = t >> 2;
  int lk8  = (t & 3) * 8;
  int la = l & 15, lg = l >> 4;
  for (int k0 = 0; k0 < DM; k0 += 32){
    *(s16x8*)&As[lrow][lk8] = *(const s16x8*)&A[(size_t)(i0+lrow)*DM + k0 + lk8];
    *(s16x8*)&Bs[lrow][lk8] = *(const s16x8*)&Bt[(size_t)(n0+lrow)*DM + k0 + lk8];
    __syncthreads();
    #pragma unroll
    for (int h = 0; h < 2; ++h){
      s16x8 a = *(const s16x8*)&As[wr*32 + h*16 + la][lg*8];
      #pragma unroll
      for (int c = 0; c < 2; ++c){
        s16x8 bfr = *(const s16x8*)&Bs[wc*32 + c*16 + la][lg*8];
        acc[h][c] = __builtin_amdgcn_mfma_f32_16x16x32_bf16(a, bfr, acc[h][c], 0, 0, 0);
      }
    }
    __syncthreads();
  }
  #pragma unroll
  for (int h = 0; h < 2; ++h){
    #pragma unroll
    for (int c = 0; c < 2; ++c){
      int col = n0 + wc*32 + c*16 + la;
      #pragma unroll
      for (int r = 0; r < 4; ++r){
        int row = i0 + wr*32 + h*16 + lg*4 + r;
        float v = acc[h][c][r];
        if (mode == 0) outf[(size_t)row*DM + col] = v + bias[col];
        else           outb[(size_t)row*DM + col] = f2bf(v + addf[(size_t)row*DM + col]);
      }
    }
  }
}

// ---------------- transpose ve -> vt[b][d][j] ----------------
__global__ __launch_bounds__(256) void k_vt(const short* __restrict__ ve, short* __restrict__ vt){
  int j0 = blockIdx.x*32, d0 = blockIdx.y*32, b = blockIdx.z;
  __shared__ short tile[32][36];
  int t = threadIdx.x;
  int r = t >> 3, c4 = (t & 7)*4;
  const short* vb = ve + (size_t)b*NN*DM;
  *(s16x4*)&tile[r][c4] = *(const s16x4*)&vb[(size_t)(j0+r)*DM + d0 + c4];
  __syncthreads();
  s16x4 o;
  #pragma unroll
  for (int e=0;e<4;++e) o[e] = tile[c4+e][r];
  short* ob = vt + (size_t)b*DM*NN;
  *(s16x4*)&ob[(size_t)(d0+r)*NN + j0 + c4] = o;
}

// ---------------- streaming attention (no max-subtract; scores bounded) ----------------
// block: 32 q-rows x full D=512, 4 waves split K for S, LDS-reduce, then P@V^T
__global__ __launch_bounds__(256) void k_attn(const short* __restrict__ qe, const short* __restrict__ ke,
        const short* __restrict__ vt, float* __restrict__ attn){
  int i0 = blockIdx.x*32; int b = blockIdx.y;
  int t = threadIdx.x; int w = t>>6; int l = t&63;
  __shared__ unsigned char qlds[32*1040];   // rows padded to 1040B (520 shorts)
  __shared__ float sred[4][32][33];
  __shared__ unsigned char plds[32*80];     // rows padded to 40 shorts
  __shared__ float psum[32][9];
  __shared__ float lsum[32];
  const short* qb = qe + (size_t)b*NN*DM;
  const short* kb = ke + (size_t)b*NN*DM;
  const short* vb = vt + (size_t)b*DM*NN;
  #pragma unroll
  for (int it = 0; it < 8; ++it){
    int idx = it*256 + t;
    int r = idx >> 6, ch = idx & 63;
    *(s16x8*)&qlds[r*1040 + ch*16] = *(const s16x8*)&qb[(size_t)(i0+r)*DM + ch*8];
  }
  if (t < 32) lsum[t] = 0.f;
  f32x4 O[2][8];
  #pragma unroll
  for (int h=0;h<2;++h)
    #pragma unroll
    for (int n=0;n<8;++n) O[h][n] = (f32x4){0.f,0.f,0.f,0.f};
  __syncthreads();
  const float scale = 0.044194173824159216f;  // 1/sqrt(512)
  int la = l & 15, lg = l >> 4;
  for (int jt = 0; jt < 64; ++jt){
    int j0 = jt*32;
    f32x4 sacc[2][2];
    #pragma unroll
    for (int h=0;h<2;++h)
      #pragma unroll
      for (int c=0;c<2;++c) sacc[h][c] = (f32x4){0.f,0.f,0.f,0.f};
    #pragma unroll
    for (int ks = 0; ks < 4; ++ks){
      int kk = w*128 + ks*32;
      s16x8 a0 = *(const s16x8*)&qlds[(size_t)la*1040 + kk*2 + lg*16];
      s16x8 a1 = *(const s16x8*)&qlds[(size_t)(la+16)*1040 + kk*2 + lg*16];
      s16x8 b0 = *(const s16x8*)&kb[(size_t)(j0 + la)*DM + kk + lg*8];
      s16x8 b1 = *(const s16x8*)&kb[(size_t)(j0 + 16 + la)*DM + kk + lg*8];
      sacc[0][0] = __builtin_amdgcn_mfma_f32_16x16x32_bf16(a0, b0, sacc[0][0], 0,0,0);
      sacc[0][1] = __builtin_amdgcn_mfma_f32_16x16x32_bf16(a0, b1, sacc[0][1], 0,0,0);
      sacc[1][0] = __builtin_amdgcn_mfma_f32_16x16x32_bf16(a1, b0, sacc[1][0], 0,0,0);
      sacc[1][1] = __builtin_amdgcn_mfma_f32_16x16x32_bf16(a1, b1, sacc[1][1], 0,0,0);
    }
    #pragma unroll
    for (int h=0;h<2;++h)
      #pragma unroll
      for (int c=0;c<2;++c)
        #pragma unroll
        for (int r=0;r<4;++r)
          sred[w][h*16 + lg*4 + r][c*16 + la] = sacc[h][c][r];
    __syncthreads();
    {
      int i = t >> 3; int cg = (t & 7)*4;
      float ps = 0.f;
      s16x4 pb;
      #pragma unroll
      for (int e = 0; e < 4; ++e){
        int c = cg + e;
        float s = sred[0][i][c] + sred[1][i][c] + sred[2][i][c] + sred[3][i][c];
        float p = __expf(s * scale);
        ps += p;
        pb[e] = f2bf(p);
      }
      *(s16x4*)&plds[i*80 + cg*2] = pb;
      psum[i][t & 7] = ps;
    }
    __syncthreads();
    if (t < 32){
      float s2 = 0.f;
      #pragma unroll
      for (int e=0;e<8;++e) s2 += psum[t][e];
      lsum[t] += s2;
    }
    s16x8 pa0 = *(const s16x8*)&plds[la*80 + lg*16];
    s16x8 pa1 = *(const s16x8*)&plds[(la+16)*80 + lg*16];
    #pragma unroll
    for (int nt = 0; nt < 8; ++nt){
      int d = w*128 + nt*16 + la;
      s16x8 bv = *(const s16x8*)&vb[(size_t)d*NN + j0 + lg*8];
      O[0][nt] = __builtin_amdgcn_mfma_f32_16x16x32_bf16(pa0, bv, O[0][nt], 0,0,0);
      O[1][nt] = __builtin_amdgcn_mfma_f32_16x16x32_bf16(pa1, bv, O[1][nt], 0,0,0);
    }
    __syncthreads();
  }
  float* ab = attn + (size_t)b*NN*DM;
  #pragma unroll
  for (int h = 0; h < 2; ++h){
    #pragma unroll
    for (int nt = 0; nt < 8; ++nt){
      int col = w*128 + nt*16 + la;
      #pragma unroll
      for (int r = 0; r < 4; ++r){
        int rl = h*16 + lg*4 + r;
        ab[(size_t)(i0 + rl)*DM + col] = O[h][nt][r] / lsum[rl];
      }
    }
  }
}

// ---------------- res = attn@W2 + b2 + features (f32) ----------------
__global__ __launch_bounds__(256) void k_res(const float* __restrict__ attn, const float* __restrict__ W2,
       const float* __restrict__ b2, const float* __restrict__ feat, float* __restrict__ res){
  int r0 = blockIdx.x * 4;
  int t = threadIdx.x;
  __shared__ float al[4][DM];
  for (int idx = t; idx < 4*DM; idx += 256){
    al[idx>>9][idx&511] = attn[(size_t)r0*DM + idx];
  }
  __syncthreads();
  int rr = t >> 6, c = t & 63;
  int row = r0 + rr;
  float acc = b2[c];
  #pragma unroll 8
  for (int k = 0; k < DM; ++k) acc += al[rr][k]*W2[(size_t)k*DP + c];
  res[(size_t)row*DP + c] = acc + feat[(size_t)row*DP + c];
}

extern "C" void kernel_launch(void* const* d_in, const int* in_sizes, int n_in,
                              void* d_out, int out_size, void* d_ws, size_t ws_size,
                              hipStream_t stream){
  const float* xyz  = (const float*)d_in[0];
  const float* feat = (const float*)d_in[1];
  const float* W1   = (const float*)d_in[2];
  const float* b1   = (const float*)d_in[3];
  const float* W2   = (const float*)d_in[4];
  const float* b2   = (const float*)d_in[5];
  const float* Wd1  = (const float*)d_in[6];
  const float* bd1  = (const float*)d_in[7];
  const float* Wd2  = (const float*)d_in[8];
  const float* bd2  = (const float*)d_in[9];
  const float* Wq   = (const float*)d_in[10];
  const float* Wk   = (const float*)d_in[11];
  const float* Wv   = (const float*)d_in[12];
  // d_in[13] = k (ignored, hardcoded 16)

  char* ws = (char*)d_ws;                        // needs ~110 MB
  float* sq    = (float*)(ws + (0ull<<20));
  int*   kidx  = (int*)  (ws + (1ull<<20));
  float* kw    = (float*)(ws + (2ull<<20));
  float* wsum  = (float*)(ws + (3ull<<20));
  short* Wqt   = (short*)(ws + (4ull<<20));
  short* Wkt   = Wqt + (size_t)DM*DM;
  short* Wvt   = Wkt + (size_t)DM*DM;
  short* Wd2t  = Wvt + (size_t)DM*DM;
  short* Prelu = (short*)(ws + (8ull<<20));      // 16.75MB; reused as qe
  short* g     = (short*)(ws + (25ull<<20));     // 16.75MB; reused as ke
  short* x     = (short*)(ws + (42ull<<20));     // 16.75MB
  float* wa    = (float*)(ws + (59ull<<20));     // 33.5MB; first half reused as vt
  short* ve    = (short*)(ws + (93ull<<20));     // 16.75MB
  short* qe = Prelu; short* ke = g; short* vt = (short*)wa;

  float* res  = (float*)d_out;
  float* attn = (float*)d_out + (size_t)ROWS*DP;

  k_sq   <<<ROWS/256, 256, 0, stream>>>(xyz, sq);
  k_knn  <<<ROWS, 256, 0, stream>>>(xyz, sq, kidx, kw, wsum);
  k_prep <<<(4*DM*DM)/256, 256, 0, stream>>>(Wq, Wk, Wv, Wd2, Wqt, Wkt, Wvt, Wd2t);
  k_prelu<<<(ROWS*DM)/256, 256, 0, stream>>>(xyz, Wd1, bd1, Prelu);
  k_fc1  <<<ROWS/4, 256, 0, stream>>>(feat, W1, b1, x);
  k_g    <<<ROWS, 256, 0, stream>>>(Prelu, kidx, kw, wsum, g);
  k_gemm <<<dim3(ROWS/64, DM/64), 256, 0, stream>>>(g, Wd2t, bd2, nullptr, wa, nullptr, 0);
  k_gemm <<<dim3(ROWS/64, DM/64), 256, 0, stream>>>(x, Wqt, nullptr, wa, nullptr, qe, 1);
  k_gemm <<<dim3(ROWS/64, DM/64), 256, 0, stream>>>(x, Wkt, nullptr, wa, nullptr, ke, 1);
  k_gemm <<<dim3(ROWS/64, DM/64), 256, 0, stream>>>(x, Wvt, nullptr, wa, nullptr, ve, 1);
  k_vt   <<<dim3(NN/32, DM/32, BB), 256, 0, stream>>>(ve, vt);
  k_attn <<<dim3(NN/32, BB), 256, 0, stream>>>(qe, ke, vt, attn);
  k_res  <<<ROWS/4, 256, 0, stream>>>(attn, W2, b2, feat, res);
}

// Round 2
// 624.686 us; speedup vs baseline: 1.1959x; 1.1959x over previous
//
#include <hip/hip_runtime.h>

#define BB 8
#define NN 2048
#define DP 64
#define DM 512
#define KNNK 16
#define ROWS (BB*NN)   // 16384

typedef __attribute__((ext_vector_type(8))) short s16x8;
typedef __attribute__((ext_vector_type(4))) short s16x4;
typedef __attribute__((ext_vector_type(4))) float f32x4;

__device__ __forceinline__ float bf2f(short u){
  union { unsigned int i; float f; } v; v.i = ((unsigned int)(unsigned short)u) << 16; return v.f;
}
__device__ __forceinline__ short f2bf(float f){
  union { float f; unsigned int i; } v; v.f = f;
  unsigned int x = v.i;
  return (short)((x + 0x7fffu + ((x >> 16) & 1u)) >> 16);
}

// global -> LDS direct (16B per lane). CK-style addrspace cast.
__device__ __forceinline__ void gload16(const void* g, void* l){
  __builtin_amdgcn_global_load_lds(
      (const __attribute__((address_space(1))) void*)(__UINTPTR_TYPE__)g,
      (__attribute__((address_space(3))) void*)(__UINTPTR_TYPE__)l, 16, 0, 0);
}

// ---------------- sq = ||xyz||^2 ----------------
__global__ void k_sq(const float* __restrict__ xyz, float* __restrict__ sq){
  int i = blockIdx.x*256 + threadIdx.x;
  if (i < ROWS){
    float x = xyz[3*i], y = xyz[3*i+1], z = xyz[3*i+2];
    sq[i] = x*x + y*y + z*z;
  }
}

// ---------------- exact knn: iterative argmin, wave-level shfl reduce ----------------
__global__ __launch_bounds__(256) void k_knn(const float* __restrict__ xyz, const float* __restrict__ sq,
        int* __restrict__ kidx, float* __restrict__ kw, float* __restrict__ wsum){
  int row = blockIdx.x;
  int b = row >> 11; int i = row & (NN-1);
  const float* xb = xyz + (size_t)b*NN*3;
  const float* sqb = sq + (size_t)b*NN;
  int t = threadIdx.x; int w = t >> 6; int l = t & 63;
  __shared__ float dloc[NN];
  __shared__ float rv[4];
  __shared__ int   ri[4];
  float xi0 = xb[3*i], xi1 = xb[3*i+1], xi2 = xb[3*i+2];
  float sqi = sqb[i];
  for (int j = t; j < NN; j += 256){
    float d = sqi + sqb[j] - 2.0f*(xi0*xb[3*j] + xi1*xb[3*j+1] + xi2*xb[3*j+2]);
    dloc[j] = d;
  }
  __syncthreads();
  float wacc = 0.f;
  for (int sel = 0; sel < KNNK; ++sel){
    float best = 3.0e38f; int bi = NN;
    for (int j = t; j < NN; j += 256){
      float d = dloc[j];
      if (d < best){ best = d; bi = j; }
    }
    #pragma unroll
    for (int off = 32; off > 0; off >>= 1){
      float ov = __shfl_xor(best, off);
      int   oi = __shfl_xor(bi, off);
      if (ov < best || (ov == best && oi < bi)){ best = ov; bi = oi; }
    }
    if (l == 0){ rv[w] = best; ri[w] = bi; }
    __syncthreads();
    if (t == 0){
      float bb = rv[0]; int bj = ri[0];
      #pragma unroll
      for (int m = 1; m < 4; ++m){
        if (rv[m] < bb || (rv[m] == bb && ri[m] < bj)){ bb = rv[m]; bj = ri[m]; }
      }
      dloc[bj] = 3.0e38f;
      kidx[(size_t)row*KNNK + sel] = bj;
      float wg = 1.0f/(bb + 1e-6f);
      kw[(size_t)row*KNNK + sel] = wg;
      wacc += wg;
    }
    __syncthreads();
  }
  if (t == 0) wsum[row] = wacc;
}

// ---------------- convert+transpose the 512x512 weights to bf16 [n][k] ----------------
__global__ void k_prep(const float* __restrict__ Wq, const float* __restrict__ Wk,
                       const float* __restrict__ Wv, const float* __restrict__ Wd2,
                       short* __restrict__ Wqt, short* __restrict__ Wkt,
                       short* __restrict__ Wvt, short* __restrict__ Wd2t){
  int idx = blockIdx.x*256 + threadIdx.x;   // 4*512*512
  int m = idx / (DM*DM); int r = idx % (DM*DM);
  int n = r / DM; int k = r % DM;
  const float* W = (m==0)?Wq:(m==1)?Wk:(m==2)?Wv:Wd2;
  short* Wt = (m==0)?Wqt:(m==1)?Wkt:(m==2)?Wvt:Wd2t;
  Wt[r] = f2bf(W[(size_t)k*DM + n]);
}

// ---------------- Prelu[row][d] = relu(xyz@Wd1 + bd1), bf16 ----------------
__global__ void k_prelu(const float* __restrict__ xyz, const float* __restrict__ Wd1,
                        const float* __restrict__ bd1, short* __restrict__ Prelu){
  int idx = blockIdx.x*256 + threadIdx.x;   // ROWS*DM
  int row = idx >> 9; int d = idx & (DM-1);
  float x0 = xyz[3*row], x1 = xyz[3*row+1], x2 = xyz[3*row+2];
  float v = x0*Wd1[d] + x1*Wd1[DM + d] + x2*Wd1[2*DM + d] + bd1[d];
  Prelu[idx] = f2bf(fmaxf(v, 0.f));
}

// ---------------- x = features@W1 + b1 (f32 compute, bf16 out), 4 rows/block ----------------
__global__ __launch_bounds__(256) void k_fc1(const float* __restrict__ feat, const float* __restrict__ W1,
                       const float* __restrict__ b1, short* __restrict__ x){
  int r0 = blockIdx.x*4;
  __shared__ float f[4][DP];
  int t = threadIdx.x;
  if (t < 4*DP) f[t>>6][t&63] = feat[(size_t)r0*DP + t];
  __syncthreads();
  for (int c = t; c < DM; c += 256){
    float bb = b1[c];
    float a0=bb,a1=bb,a2=bb,a3=bb;
    #pragma unroll 8
    for (int k = 0; k < DP; ++k){
      float w = W1[(size_t)k*DM + c];
      a0 += f[0][k]*w; a1 += f[1][k]*w; a2 += f[2][k]*w; a3 += f[3][k]*w;
    }
    x[(size_t)(r0+0)*DM + c] = f2bf(a0);
    x[(size_t)(r0+1)*DM + c] = f2bf(a1);
    x[(size_t)(r0+2)*DM + c] = f2bf(a2);
    x[(size_t)(r0+3)*DM + c] = f2bf(a3);
  }
}

// ---------------- g = (sum_j w_j * Prelu[idx_j]) / wsum, bf16 ----------------
__global__ __launch_bounds__(256) void k_g(const short* __restrict__ Prelu, const int* __restrict__ kidx,
                   const float* __restrict__ kw, const float* __restrict__ wsum, short* __restrict__ g){
  int row = blockIdx.x;
  int b = row >> 11;
  int t = threadIdx.x;
  __shared__ int sidx[KNNK]; __shared__ float sw[KNNK];
  if (t < KNNK){ sidx[t] = kidx[(size_t)row*KNNK + t]; sw[t] = kw[(size_t)row*KNNK + t]; }
  __syncthreads();
  float inv = 1.0f / wsum[row];
  float a0 = 0.f, a1 = 0.f;
  const short* Pb = Prelu + (size_t)b*NN*DM;
  #pragma unroll
  for (int j = 0; j < KNNK; ++j){
    const short* pr = Pb + (size_t)sidx[j]*DM;
    float wj = sw[j];
    a0 += wj*bf2f(pr[t]);
    a1 += wj*bf2f(pr[t+256]);
  }
  g[(size_t)row*DM + t]       = f2bf(a0*inv);
  g[(size_t)row*DM + t + 256] = f2bf(a1*inv);
}

// ---------------- bf16 MFMA GEMM, m97 structure: 128x128 tile, BK=32, global_load_lds ----------------
// mode 0: outf = acc + bias[col]   (f32)
// mode 1: outb = bf16(acc + addf)  (bf16)
__global__ __launch_bounds__(256) void k_gemm(const short* __restrict__ A, const short* __restrict__ Bt,
       const float* __restrict__ bias, const float* __restrict__ addf,
       float* __restrict__ outf, short* __restrict__ outb, int mode){
  __shared__ short As[128*32];
  __shared__ short Bs[128*32];
  int t = threadIdx.x;
  size_t i0 = (size_t)blockIdx.x*128, n0 = (size_t)blockIdx.y*128;
  int w = t >> 6, l = t & 63, la = l & 15, lg = l >> 4;
  int wr = w >> 1, wc = w & 1;
  f32x4 acc[4][4];
  #pragma unroll
  for (int h=0;h<4;++h)
    #pragma unroll
    for (int c=0;c<4;++c) acc[h][c] = (f32x4){0.f,0.f,0.f,0.f};
  int srow = t >> 2; int sk8 = (t & 3)*8;
  const short* Ab  = A  + (i0 + srow)*DM + sk8;
  const short* Ab2 = A  + (i0 + 64 + srow)*DM + sk8;
  const short* Bb  = Bt + (n0 + srow)*DM + sk8;
  const short* Bb2 = Bt + (n0 + 64 + srow)*DM + sk8;
  short* Asd  = &As[t*8];      short* Asd2 = &As[2048 + t*8];
  short* Bsd  = &Bs[t*8];      short* Bsd2 = &Bs[2048 + t*8];
  for (int k0 = 0; k0 < DM; k0 += 32){
    gload16(Ab  + k0, Asd);
    gload16(Ab2 + k0, Asd2);
    gload16(Bb  + k0, Bsd);
    gload16(Bb2 + k0, Bsd2);
    __syncthreads();
    s16x8 af[4], bg[4];
    #pragma unroll
    for (int h=0;h<4;++h) af[h] = *(const s16x8*)&As[(wr*64 + h*16 + la)*32 + lg*8];
    #pragma unroll
    for (int c=0;c<4;++c) bg[c] = *(const s16x8*)&Bs[(wc*64 + c*16 + la)*32 + lg*8];
    #pragma unroll
    for (int h=0;h<4;++h)
      #pragma unroll
      for (int c=0;c<4;++c)
        acc[h][c] = __builtin_amdgcn_mfma_f32_16x16x32_bf16(af[h], bg[c], acc[h][c], 0, 0, 0);
    __syncthreads();
  }
  #pragma unroll
  for (int h=0;h<4;++h){
    #pragma unroll
    for (int c=0;c<4;++c){
      size_t col = n0 + wc*64 + c*16 + la;
      #pragma unroll
      for (int r=0;r<4;++r){
        size_t row = i0 + wr*64 + h*16 + lg*4 + r;
        float v = acc[h][c][r];
        if (mode == 0) outf[row*DM + col] = v + bias[col];
        else           outb[row*DM + col] = f2bf(v + addf[row*DM + col]);
      }
    }
  }
}

// ---------------- transpose ve -> vt[b][d][j] ----------------
__global__ __launch_bounds__(256) void k_vt(const short* __restrict__ ve, short* __restrict__ vt){
  int j0 = blockIdx.x*32, d0 = blockIdx.y*32, b = blockIdx.z;
  __shared__ short tile[32][36];
  int t = threadIdx.x;
  int r = t >> 3, c4 = (t & 7)*4;
  const short* vb = ve + (size_t)b*NN*DM;
  *(s16x4*)&tile[r][c4] = *(const s16x4*)&vb[(size_t)(j0+r)*DM + d0 + c4];
  __syncthreads();
  s16x4 o;
  #pragma unroll
  for (int e=0;e<4;++e) o[e] = tile[c4+e][r];
  short* ob = vt + (size_t)b*DM*NN;
  *(s16x4*)&ob[(size_t)(d0+r)*NN + j0 + c4] = o;
}

// ---------------- attention: 64 q-rows/block, 8 waves, j-split scores, d-split PV ----------------
// Per super-iter (256 j): each wave computes its own 32-j score tile over full D (no cross-wave
// reduce), writes bf16 P to XOR-swizzled LDS, 1 barrier, then PV on its 64-d slice over all 256 j.
// Only 2 barriers per super-iter. Streaming softmax without max-subtract (scores bounded).
__global__ __launch_bounds__(512) void k_attn(const short* __restrict__ qe, const short* __restrict__ ke,
        const short* __restrict__ vt, float* __restrict__ attn){
  int bid = blockIdx.x;
  int b  = bid & 7;            // batch pinned per XCD (round-robin dispatch)
  int i0 = (bid >> 3) * 64;
  int t = threadIdx.x, w = t >> 6, l = t & 63, la = l & 15, lg = l >> 4;
  __shared__ short qlds[64*520];   // row stride 1040B -> bank-slot rotates per row
  __shared__ short plds[64*256];   // row stride 512B, XOR-swizzled by ((q&7)<<4)
  __shared__ float lsred[8][64];
  const short* qb = qe + (size_t)b*NN*DM;
  const short* kb = ke + (size_t)b*NN*DM;
  const short* vb = vt + (size_t)b*DM*NN;

  #pragma unroll
  for (int it = 0; it < 8; ++it){
    int idx = it*512 + t;          // 0..4095 chunks of 8 shorts
    int r = idx >> 6, ch = idx & 63;
    *(s16x8*)&qlds[r*520 + ch*8] = *(const s16x8*)&qb[(size_t)(i0+r)*DM + ch*8];
  }
  f32x4 Oa[4][4];
  float plsum[16];
  #pragma unroll
  for (int qh=0;qh<4;++qh){
    #pragma unroll
    for (int dt=0;dt<4;++dt) Oa[qh][dt] = (f32x4){0.f,0.f,0.f,0.f};
    #pragma unroll
    for (int r=0;r<4;++r) plsum[qh*4+r] = 0.f;
  }
  __syncthreads();
  const float scale = 0.044194173824159216f;  // 1/sqrt(512)

  for (int jt = 0; jt < 8; ++jt){
    int j0 = jt*256;
    int jw = j0 + w*32;
    f32x4 sacc[4][2];
    #pragma unroll
    for (int qh=0;qh<4;++qh){ sacc[qh][0] = (f32x4){0.f,0.f,0.f,0.f}; sacc[qh][1] = (f32x4){0.f,0.f,0.f,0.f}; }
    #pragma unroll
    for (int ks = 0; ks < 16; ++ks){
      int kk = ks*32;
      s16x8 b0 = *(const s16x8*)&kb[(size_t)(jw + la)*DM + kk + lg*8];
      s16x8 b1 = *(const s16x8*)&kb[(size_t)(jw + 16 + la)*DM + kk + lg*8];
      #pragma unroll
      for (int qh = 0; qh < 4; ++qh){
        s16x8 a = *(const s16x8*)&qlds[(qh*16 + la)*520 + kk + lg*8];
        sacc[qh][0] = __builtin_amdgcn_mfma_f32_16x16x32_bf16(a, b0, sacc[qh][0], 0,0,0);
        sacc[qh][1] = __builtin_amdgcn_mfma_f32_16x16x32_bf16(a, b1, sacc[qh][1], 0,0,0);
      }
    }
    // exp -> P (bf16, swizzled LDS) + register row-sums
    #pragma unroll
    for (int qh = 0; qh < 4; ++qh){
      #pragma unroll
      for (int c = 0; c < 2; ++c){
        int jloc = w*32 + c*16 + la;
        #pragma unroll
        for (int r = 0; r < 4; ++r){
          int q = qh*16 + lg*4 + r;
          float p = __expf(sacc[qh][c][r]*scale);
          plsum[qh*4+r] += p;
          int byt = (q*512 + jloc*2) ^ ((q&7)<<4);
          *(short*)((char*)plds + byt) = f2bf(p);
        }
      }
    }
    __syncthreads();
    // PV: wave's 64-d slice over this super-iter's 256 j
    int d0 = w*64;
    #pragma unroll
    for (int js = 0; js < 8; ++js){
      s16x8 pa[4];
      #pragma unroll
      for (int qh = 0; qh < 4; ++qh){
        int byt = ((qh*16 + la)*512 + js*64 + lg*16) ^ ((la&7)<<4);
        pa[qh] = *(const s16x8*)((const char*)plds + byt);
      }
      #pragma unroll
      for (int dt = 0; dt < 4; ++dt){
        s16x8 bv = *(const s16x8*)&vb[(size_t)(d0 + dt*16 + la)*NN + j0 + js*32 + lg*8];
        #pragma unroll
        for (int qh = 0; qh < 4; ++qh)
          Oa[qh][dt] = __builtin_amdgcn_mfma_f32_16x16x32_bf16(pa[qh], bv, Oa[qh][dt], 0,0,0);
      }
    }
    __syncthreads();
  }
  // row-sum reduce: shfl over la within wave, LDS across waves
  #pragma unroll
  for (int m = 1; m < 16; m <<= 1){
    #pragma unroll
    for (int i = 0; i < 16; ++i) plsum[i] += __shfl_xor(plsum[i], m);
  }
  if (la == 0){
    #pragma unroll
    for (int qh = 0; qh < 4; ++qh)
      #pragma unroll
      for (int r = 0; r < 4; ++r)
        lsred[w][qh*16 + lg*4 + r] = plsum[qh*4+r];
  }
  __syncthreads();
  if (t < 64){
    float s = 0.f;
    #pragma unroll
    for (int ww = 0; ww < 8; ++ww) s += lsred[ww][t];
    lsred[0][t] = 1.0f/s;
  }
  __syncthreads();
  float* ab = attn + (size_t)b*NN*DM;
  int d0 = w*64;
  #pragma unroll
  for (int qh = 0; qh < 4; ++qh){
    #pragma unroll
    for (int r = 0; r < 4; ++r){
      int q = qh*16 + lg*4 + r;
      float linv = lsred[0][q];
      #pragma unroll
      for (int dt = 0; dt < 4; ++dt)
        ab[(size_t)(i0+q)*DM + d0 + dt*16 + la] = Oa[qh][dt][r]*linv;
    }
  }
}

// ---------------- res = attn@W2 + b2 + features (f32) ----------------
__global__ __launch_bounds__(256) void k_res(const float* __restrict__ attn, const float* __restrict__ W2,
       const float* __restrict__ b2, const float* __restrict__ feat, float* __restrict__ res){
  int r0 = blockIdx.x * 4;
  int t = threadIdx.x;
  __shared__ float al[4][DM];
  for (int idx = t; idx < 4*DM; idx += 256){
    al[idx>>9][idx&511] = attn[(size_t)r0*DM + idx];
  }
  __syncthreads();
  int rr = t >> 6, c = t & 63;
  int row = r0 + rr;
  float acc = b2[c];
  #pragma unroll 8
  for (int k = 0; k < DM; ++k) acc += al[rr][k]*W2[(size_t)k*DP + c];
  res[(size_t)row*DP + c] = acc + feat[(size_t)row*DP + c];
}

extern "C" void kernel_launch(void* const* d_in, const int* in_sizes, int n_in,
                              void* d_out, int out_size, void* d_ws, size_t ws_size,
                              hipStream_t stream){
  const float* xyz  = (const float*)d_in[0];
  const float* feat = (const float*)d_in[1];
  const float* W1   = (const float*)d_in[2];
  const float* b1   = (const float*)d_in[3];
  const float* W2   = (const float*)d_in[4];
  const float* b2   = (const float*)d_in[5];
  const float* Wd1  = (const float*)d_in[6];
  const float* bd1  = (const float*)d_in[7];
  const float* Wd2  = (const float*)d_in[8];
  const float* bd2  = (const float*)d_in[9];
  const float* Wq   = (const float*)d_in[10];
  const float* Wk   = (const float*)d_in[11];
  const float* Wv   = (const float*)d_in[12];
  // d_in[13] = k (ignored, hardcoded 16)

  char* ws = (char*)d_ws;                        // ~110 MB
  float* sq    = (float*)(ws + (0ull<<20));
  int*   kidx  = (int*)  (ws + (1ull<<20));
  float* kw    = (float*)(ws + (2ull<<20));
  float* wsum  = (float*)(ws + (3ull<<20));
  short* Wqt   = (short*)(ws + (4ull<<20));
  short* Wkt   = Wqt + (size_t)DM*DM;
  short* Wvt   = Wkt + (size_t)DM*DM;
  short* Wd2t  = Wvt + (size_t)DM*DM;
  short* Prelu = (short*)(ws + (8ull<<20));      // reused as qe
  short* g     = (short*)(ws + (25ull<<20));     // reused as ke
  short* x     = (short*)(ws + (42ull<<20));
  float* wa    = (float*)(ws + (59ull<<20));     // first half reused as vt
  short* ve    = (short*)(ws + (93ull<<20));
  short* qe = Prelu; short* ke = g; short* vt = (short*)wa;

  float* res  = (float*)d_out;
  float* attn = (float*)d_out + (size_t)ROWS*DP;

  k_sq   <<<ROWS/256, 256, 0, stream>>>(xyz, sq);
  k_knn  <<<ROWS, 256, 0, stream>>>(xyz, sq, kidx, kw, wsum);
  k_prep <<<(4*DM*DM)/256, 256, 0, stream>>>(Wq, Wk, Wv, Wd2, Wqt, Wkt, Wvt, Wd2t);
  k_prelu<<<(ROWS*DM)/256, 256, 0, stream>>>(xyz, Wd1, bd1, Prelu);
  k_fc1  <<<ROWS/4, 256, 0, stream>>>(feat, W1, b1, x);
  k_g    <<<ROWS, 256, 0, stream>>>(Prelu, kidx, kw, wsum, g);
  k_gemm <<<dim3(ROWS/128, DM/128), 256, 0, stream>>>(g, Wd2t, bd2, nullptr, wa, nullptr, 0);
  k_gemm <<<dim3(ROWS/128, DM/128), 256, 0, stream>>>(x, Wqt, nullptr, wa, nullptr, qe, 1);
  k_gemm <<<dim3(ROWS/128, DM/128), 256, 0, stream>>>(x, Wkt, nullptr, wa, nullptr, ke, 1);
  k_gemm <<<dim3(ROWS/128, DM/128), 256, 0, stream>>>(x, Wvt, nullptr, wa, nullptr, ve, 1);
  k_vt   <<<dim3(NN/32, DM/32, BB), 256, 0, stream>>>(ve, vt);
  k_attn <<<dim3(NN/64 * BB), 512, 0, stream>>>(qe, ke, vt, attn);
  k_res  <<<ROWS/4, 256, 0, stream>>>(attn, W2, b2, feat, res);
}

// Round 3
// 529.708 us; speedup vs baseline: 1.4103x; 1.1793x over previous
//
#include <hip/hip_runtime.h>

#define BB 8
#define NN 2048
#define DP 64
#define DM 512
#define KNNK 16
#define ROWS (BB*NN)   // 16384

typedef __attribute__((ext_vector_type(8))) short s16x8;
typedef __attribute__((ext_vector_type(4))) short s16x4;
typedef __attribute__((ext_vector_type(4))) float f32x4;

__device__ __forceinline__ float bf2f(short u){
  union { unsigned int i; float f; } v; v.i = ((unsigned int)(unsigned short)u) << 16; return v.f;
}
__device__ __forceinline__ short f2bf(float f){
  union { float f; unsigned int i; } v; v.f = f;
  unsigned int x = v.i;
  return (short)((x + 0x7fffu + ((x >> 16) & 1u)) >> 16);
}

// global -> LDS direct (16B per lane). CK-style addrspace cast.
__device__ __forceinline__ void gload16(const void* g, void* l){
  __builtin_amdgcn_global_load_lds(
      (const __attribute__((address_space(1))) void*)(__UINTPTR_TYPE__)g,
      (__attribute__((address_space(3))) void*)(__UINTPTR_TYPE__)l, 16, 0, 0);
}

// ---------------- sq = ||xyz||^2 ----------------
__global__ void k_sq(const float* __restrict__ xyz, float* __restrict__ sq){
  int i = blockIdx.x*256 + threadIdx.x;
  if (i < ROWS){
    float x = xyz[3*i], y = xyz[3*i+1], z = xyz[3*i+2];
    sq[i] = x*x + y*y + z*z;
  }
}

// ---------------- exact knn: wave-per-row, dists in 32 VGPRs, zero barriers ----------------
// j = e*64 + lane. 16 iterative extractions: per-lane unrolled argmin scan,
// 6-step shfl_xor argmin reduce (smaller-j tiebreak), unrolled invalidate.
__global__ __launch_bounds__(256) void k_knn(const float* __restrict__ xyz, const float* __restrict__ sq,
        int* __restrict__ kidx, float* __restrict__ kw, float* __restrict__ wsum){
  int row = blockIdx.x*4 + (threadIdx.x >> 6);
  int l = threadIdx.x & 63;
  int b = row >> 11; int i = row & (NN-1);
  const float* xb = xyz + (size_t)b*NN*3;
  const float* sqb = sq + (size_t)b*NN;
  float xi0 = xb[3*i], xi1 = xb[3*i+1], xi2 = xb[3*i+2];
  float sqi = sqb[i];
  float d[32];
  #pragma unroll
  for (int e = 0; e < 32; ++e){
    int j = e*64 + l;
    d[e] = sqi + sqb[j] - 2.0f*(xi0*xb[3*j] + xi1*xb[3*j+1] + xi2*xb[3*j+2]);
  }
  float wacc = 0.f;
  for (int sel = 0; sel < KNNK; ++sel){
    // per-lane argmin over 32 regs (strict < keeps smallest e on ties -> smallest j)
    float best = d[0]; int be = 0;
    #pragma unroll
    for (int e = 1; e < 32; ++e){
      bool c = d[e] < best;
      be = c ? e : be;
      best = c ? d[e] : best;
    }
    int bidx = be*64 + l;
    // wave argmin, smaller-j tiebreak
    #pragma unroll
    for (int off = 32; off > 0; off >>= 1){
      float ov = __shfl_xor(best, off);
      int   oi = __shfl_xor(bidx, off);
      bool c = (ov < best) || (ov == best && oi < bidx);
      best = c ? ov : best;
      bidx = c ? oi : bidx;
    }
    float wg = 1.0f/(best + 1e-6f);
    wacc += wg;
    if (l == 0){
      kidx[(size_t)row*KNNK + sel] = bidx;
      kw[(size_t)row*KNNK + sel] = wg;
    }
    // invalidate extracted element
    int pe = bidx >> 6, pl = bidx & 63;
    bool mine = (l == pl);
    #pragma unroll
    for (int e = 0; e < 32; ++e)
      if (e == pe && mine) d[e] = 3.0e38f;
  }
  if (l == 0) wsum[row] = wacc;
}

// ---------------- convert+transpose the 512x512 weights to bf16 [n][k] ----------------
__global__ void k_prep(const float* __restrict__ Wq, const float* __restrict__ Wk,
                       const float* __restrict__ Wv, const float* __restrict__ Wd2,
                       short* __restrict__ Wqt, short* __restrict__ Wkt,
                       short* __restrict__ Wvt, short* __restrict__ Wd2t){
  int idx = blockIdx.x*256 + threadIdx.x;   // 4*512*512
  int m = idx / (DM*DM); int r = idx % (DM*DM);
  int n = r / DM; int k = r % DM;
  const float* W = (m==0)?Wq:(m==1)?Wk:(m==2)?Wv:Wd2;
  short* Wt = (m==0)?Wqt:(m==1)?Wkt:(m==2)?Wvt:Wd2t;
  Wt[r] = f2bf(W[(size_t)k*DM + n]);
}

// ---------------- Prelu[row][d] = relu(xyz@Wd1 + bd1), bf16 ----------------
__global__ void k_prelu(const float* __restrict__ xyz, const float* __restrict__ Wd1,
                        const float* __restrict__ bd1, short* __restrict__ Prelu){
  int idx = blockIdx.x*256 + threadIdx.x;   // ROWS*DM
  int row = idx >> 9; int d = idx & (DM-1);
  float x0 = xyz[3*row], x1 = xyz[3*row+1], x2 = xyz[3*row+2];
  float v = x0*Wd1[d] + x1*Wd1[DM + d] + x2*Wd1[2*DM + d] + bd1[d];
  Prelu[idx] = f2bf(fmaxf(v, 0.f));
}

// ---------------- x = features@W1 + b1 (f32 compute, bf16 out), 4 rows/block ----------------
__global__ __launch_bounds__(256) void k_fc1(const float* __restrict__ feat, const float* __restrict__ W1,
                       const float* __restrict__ b1, short* __restrict__ x){
  int r0 = blockIdx.x*4;
  __shared__ float f[4][DP];
  int t = threadIdx.x;
  if (t < 4*DP) f[t>>6][t&63] = feat[(size_t)r0*DP + t];
  __syncthreads();
  for (int c = t; c < DM; c += 256){
    float bb = b1[c];
    float a0=bb,a1=bb,a2=bb,a3=bb;
    #pragma unroll 8
    for (int k = 0; k < DP; ++k){
      float w = W1[(size_t)k*DM + c];
      a0 += f[0][k]*w; a1 += f[1][k]*w; a2 += f[2][k]*w; a3 += f[3][k]*w;
    }
    x[(size_t)(r0+0)*DM + c] = f2bf(a0);
    x[(size_t)(r0+1)*DM + c] = f2bf(a1);
    x[(size_t)(r0+2)*DM + c] = f2bf(a2);
    x[(size_t)(r0+3)*DM + c] = f2bf(a3);
  }
}

// ---------------- g = (sum_j w_j * Prelu[idx_j]) / wsum, bf16 ----------------
__global__ __launch_bounds__(256) void k_g(const short* __restrict__ Prelu, const int* __restrict__ kidx,
                   const float* __restrict__ kw, const float* __restrict__ wsum, short* __restrict__ g){
  int row = blockIdx.x;
  int b = row >> 11;
  int t = threadIdx.x;
  __shared__ int sidx[KNNK]; __shared__ float sw[KNNK];
  if (t < KNNK){ sidx[t] = kidx[(size_t)row*KNNK + t]; sw[t] = kw[(size_t)row*KNNK + t]; }
  __syncthreads();
  float inv = 1.0f / wsum[row];
  float a0 = 0.f, a1 = 0.f;
  const short* Pb = Prelu + (size_t)b*NN*DM;
  #pragma unroll
  for (int j = 0; j < KNNK; ++j){
    const short* pr = Pb + (size_t)sidx[j]*DM;
    float wj = sw[j];
    a0 += wj*bf2f(pr[t]);
    a1 += wj*bf2f(pr[t+256]);
  }
  g[(size_t)row*DM + t]       = f2bf(a0*inv);
  g[(size_t)row*DM + t + 256] = f2bf(a1*inv);
}

// ---------------- bf16 MFMA GEMM, m97 structure: 128x128 tile, BK=32, global_load_lds ----------------
// mode 0: outf = acc + bias[col]   (f32)
// mode 1: outb = bf16(acc + addf)  (bf16)
__global__ __launch_bounds__(256) void k_gemm(const short* __restrict__ A, const short* __restrict__ Bt,
       const float* __restrict__ bias, const float* __restrict__ addf,
       float* __restrict__ outf, short* __restrict__ outb, int mode){
  __shared__ short As[128*32];
  __shared__ short Bs[128*32];
  int t = threadIdx.x;
  size_t i0 = (size_t)blockIdx.x*128, n0 = (size_t)blockIdx.y*128;
  int w = t >> 6, l = t & 63, la = l & 15, lg = l >> 4;
  int wr = w >> 1, wc = w & 1;
  f32x4 acc[4][4];
  #pragma unroll
  for (int h=0;h<4;++h)
    #pragma unroll
    for (int c=0;c<4;++c) acc[h][c] = (f32x4){0.f,0.f,0.f,0.f};
  int srow = t >> 2; int sk8 = (t & 3)*8;
  const short* Ab  = A  + (i0 + srow)*DM + sk8;
  const short* Ab2 = A  + (i0 + 64 + srow)*DM + sk8;
  const short* Bb  = Bt + (n0 + srow)*DM + sk8;
  const short* Bb2 = Bt + (n0 + 64 + srow)*DM + sk8;
  short* Asd  = &As[t*8];      short* Asd2 = &As[2048 + t*8];
  short* Bsd  = &Bs[t*8];      short* Bsd2 = &Bs[2048 + t*8];
  for (int k0 = 0; k0 < DM; k0 += 32){
    gload16(Ab  + k0, Asd);
    gload16(Ab2 + k0, Asd2);
    gload16(Bb  + k0, Bsd);
    gload16(Bb2 + k0, Bsd2);
    __syncthreads();
    s16x8 af[4], bg[4];
    #pragma unroll
    for (int h=0;h<4;++h) af[h] = *(const s16x8*)&As[(wr*64 + h*16 + la)*32 + lg*8];
    #pragma unroll
    for (int c=0;c<4;++c) bg[c] = *(const s16x8*)&Bs[(wc*64 + c*16 + la)*32 + lg*8];
    #pragma unroll
    for (int h=0;h<4;++h)
      #pragma unroll
      for (int c=0;c<4;++c)
        acc[h][c] = __builtin_amdgcn_mfma_f32_16x16x32_bf16(af[h], bg[c], acc[h][c], 0, 0, 0);
    __syncthreads();
  }
  #pragma unroll
  for (int h=0;h<4;++h){
    #pragma unroll
    for (int c=0;c<4;++c){
      size_t col = n0 + wc*64 + c*16 + la;
      #pragma unroll
      for (int r=0;r<4;++r){
        size_t row = i0 + wr*64 + h*16 + lg*4 + r;
        float v = acc[h][c][r];
        if (mode == 0) outf[row*DM + col] = v + bias[col];
        else           outb[row*DM + col] = f2bf(v + addf[row*DM + col]);
      }
    }
  }
}

// ---------------- transpose ve -> vt[b][d][j] ----------------
__global__ __launch_bounds__(256) void k_vt(const short* __restrict__ ve, short* __restrict__ vt){
  int j0 = blockIdx.x*32, d0 = blockIdx.y*32, b = blockIdx.z;
  __shared__ short tile[32][36];
  int t = threadIdx.x;
  int r = t >> 3, c4 = (t & 7)*4;
  const short* vb = ve + (size_t)b*NN*DM;
  *(s16x4*)&tile[r][c4] = *(const s16x4*)&vb[(size_t)(j0+r)*DM + d0 + c4];
  __syncthreads();
  s16x4 o;
  #pragma unroll
  for (int e=0;e<4;++e) o[e] = tile[c4+e][r];
  short* ob = vt + (size_t)b*DM*NN;
  *(s16x4*)&ob[(size_t)(d0+r)*NN + j0 + c4] = o;
}

// ---------------- attention: 64 q-rows/block, 8 waves, j-split scores, d-split PV ----------------
__global__ __launch_bounds__(512) void k_attn(const short* __restrict__ qe, const short* __restrict__ ke,
        const short* __restrict__ vt, float* __restrict__ attn){
  int bid = blockIdx.x;
  int b  = bid & 7;            // batch pinned per XCD (round-robin dispatch)
  int i0 = (bid >> 3) * 64;
  int t = threadIdx.x, w = t >> 6, l = t & 63, la = l & 15, lg = l >> 4;
  __shared__ short qlds[64*520];   // row stride 1040B -> bank-slot rotates per row
  __shared__ short plds[64*256];   // row stride 512B, XOR-swizzled by ((q&7)<<4)
  __shared__ float lsred[8][64];
  const short* qb = qe + (size_t)b*NN*DM;
  const short* kb = ke + (size_t)b*NN*DM;
  const short* vb = vt + (size_t)b*DM*NN;

  #pragma unroll
  for (int it = 0; it < 8; ++it){
    int idx = it*512 + t;          // 0..4095 chunks of 8 shorts
    int r = idx >> 6, ch = idx & 63;
    *(s16x8*)&qlds[r*520 + ch*8] = *(const s16x8*)&qb[(size_t)(i0+r)*DM + ch*8];
  }
  f32x4 Oa[4][4];
  float plsum[16];
  #pragma unroll
  for (int qh=0;qh<4;++qh){
    #pragma unroll
    for (int dt=0;dt<4;++dt) Oa[qh][dt] = (f32x4){0.f,0.f,0.f,0.f};
    #pragma unroll
    for (int r=0;r<4;++r) plsum[qh*4+r] = 0.f;
  }
  __syncthreads();
  const float scale = 0.044194173824159216f;  // 1/sqrt(512)

  for (int jt = 0; jt < 8; ++jt){
    int j0 = jt*256;
    int jw = j0 + w*32;
    f32x4 sacc[4][2];
    #pragma unroll
    for (int qh=0;qh<4;++qh){ sacc[qh][0] = (f32x4){0.f,0.f,0.f,0.f}; sacc[qh][1] = (f32x4){0.f,0.f,0.f,0.f}; }
    #pragma unroll
    for (int ks = 0; ks < 16; ++ks){
      int kk = ks*32;
      s16x8 b0 = *(const s16x8*)&kb[(size_t)(jw + la)*DM + kk + lg*8];
      s16x8 b1 = *(const s16x8*)&kb[(size_t)(jw + 16 + la)*DM + kk + lg*8];
      #pragma unroll
      for (int qh = 0; qh < 4; ++qh){
        s16x8 a = *(const s16x8*)&qlds[(qh*16 + la)*520 + kk + lg*8];
        sacc[qh][0] = __builtin_amdgcn_mfma_f32_16x16x32_bf16(a, b0, sacc[qh][0], 0,0,0);
        sacc[qh][1] = __builtin_amdgcn_mfma_f32_16x16x32_bf16(a, b1, sacc[qh][1], 0,0,0);
      }
    }
    // exp -> P (bf16, swizzled LDS) + register row-sums
    #pragma unroll
    for (int qh = 0; qh < 4; ++qh){
      #pragma unroll
      for (int c = 0; c < 2; ++c){
        int jloc = w*32 + c*16 + la;
        #pragma unroll
        for (int r = 0; r < 4; ++r){
          int q = qh*16 + lg*4 + r;
          float p = __expf(sacc[qh][c][r]*scale);
          plsum[qh*4+r] += p;
          int byt = (q*512 + jloc*2) ^ ((q&7)<<4);
          *(short*)((char*)plds + byt) = f2bf(p);
        }
      }
    }
    __syncthreads();
    // PV: wave's 64-d slice over this super-iter's 256 j
    int d0 = w*64;
    #pragma unroll
    for (int js = 0; js < 8; ++js){
      s16x8 pa[4];
      #pragma unroll
      for (int qh = 0; qh < 4; ++qh){
        int byt = ((qh*16 + la)*512 + js*64 + lg*16) ^ ((la&7)<<4);
        pa[qh] = *(const s16x8*)((const char*)plds + byt);
      }
      #pragma unroll
      for (int dt = 0; dt < 4; ++dt){
        s16x8 bv = *(const s16x8*)&vb[(size_t)(d0 + dt*16 + la)*NN + j0 + js*32 + lg*8];
        #pragma unroll
        for (int qh = 0; qh < 4; ++qh)
          Oa[qh][dt] = __builtin_amdgcn_mfma_f32_16x16x32_bf16(pa[qh], bv, Oa[qh][dt], 0,0,0);
      }
    }
    __syncthreads();
  }
  // row-sum reduce: shfl over la within wave, LDS across waves
  #pragma unroll
  for (int m = 1; m < 16; m <<= 1){
    #pragma unroll
    for (int i = 0; i < 16; ++i) plsum[i] += __shfl_xor(plsum[i], m);
  }
  if (la == 0){
    #pragma unroll
    for (int qh = 0; qh < 4; ++qh)
      #pragma unroll
      for (int r = 0; r < 4; ++r)
        lsred[w][qh*16 + lg*4 + r] = plsum[qh*4+r];
  }
  __syncthreads();
  if (t < 64){
    float s = 0.f;
    #pragma unroll
    for (int ww = 0; ww < 8; ++ww) s += lsred[ww][t];
    lsred[0][t] = 1.0f/s;
  }
  __syncthreads();
  float* ab = attn + (size_t)b*NN*DM;
  int d0 = w*64;
  #pragma unroll
  for (int qh = 0; qh < 4; ++qh){
    #pragma unroll
    for (int r = 0; r < 4; ++r){
      int q = qh*16 + lg*4 + r;
      float linv = lsred[0][q];
      #pragma unroll
      for (int dt = 0; dt < 4; ++dt)
        ab[(size_t)(i0+q)*DM + d0 + dt*16 + la] = Oa[qh][dt][r]*linv;
    }
  }
}

// ---------------- res = attn@W2 + b2 + features (f32) ----------------
__global__ __launch_bounds__(256) void k_res(const float* __restrict__ attn, const float* __restrict__ W2,
       const float* __restrict__ b2, const float* __restrict__ feat, float* __restrict__ res){
  int r0 = blockIdx.x * 4;
  int t = threadIdx.x;
  __shared__ float al[4][DM];
  for (int idx = t; idx < 4*DM; idx += 256){
    al[idx>>9][idx&511] = attn[(size_t)r0*DM + idx];
  }
  __syncthreads();
  int rr = t >> 6, c = t & 63;
  int row = r0 + rr;
  float acc = b2[c];
  #pragma unroll 8
  for (int k = 0; k < DM; ++k) acc += al[rr][k]*W2[(size_t)k*DP + c];
  res[(size_t)row*DP + c] = acc + feat[(size_t)row*DP + c];
}

extern "C" void kernel_launch(void* const* d_in, const int* in_sizes, int n_in,
                              void* d_out, int out_size, void* d_ws, size_t ws_size,
                              hipStream_t stream){
  const float* xyz  = (const float*)d_in[0];
  const float* feat = (const float*)d_in[1];
  const float* W1   = (const float*)d_in[2];
  const float* b1   = (const float*)d_in[3];
  const float* W2   = (const float*)d_in[4];
  const float* b2   = (const float*)d_in[5];
  const float* Wd1  = (const float*)d_in[6];
  const float* bd1  = (const float*)d_in[7];
  const float* Wd2  = (const float*)d_in[8];
  const float* bd2  = (const float*)d_in[9];
  const float* Wq   = (const float*)d_in[10];
  const float* Wk   = (const float*)d_in[11];
  const float* Wv   = (const float*)d_in[12];
  // d_in[13] = k (ignored, hardcoded 16)

  char* ws = (char*)d_ws;                        // ~110 MB
  float* sq    = (float*)(ws + (0ull<<20));
  int*   kidx  = (int*)  (ws + (1ull<<20));
  float* kw    = (float*)(ws + (2ull<<20));
  float* wsum  = (float*)(ws + (3ull<<20));
  short* Wqt   = (short*)(ws + (4ull<<20));
  short* Wkt   = Wqt + (size_t)DM*DM;
  short* Wvt   = Wkt + (size_t)DM*DM;
  short* Wd2t  = Wvt + (size_t)DM*DM;
  short* Prelu = (short*)(ws + (8ull<<20));      // reused as qe
  short* g     = (short*)(ws + (25ull<<20));     // reused as ke
  short* x     = (short*)(ws + (42ull<<20));
  float* wa    = (float*)(ws + (59ull<<20));     // first half reused as vt
  short* ve    = (short*)(ws + (93ull<<20));
  short* qe = Prelu; short* ke = g; short* vt = (short*)wa;

  float* res  = (float*)d_out;
  float* attn = (float*)d_out + (size_t)ROWS*DP;

  k_sq   <<<ROWS/256, 256, 0, stream>>>(xyz, sq);
  k_knn  <<<ROWS/4, 256, 0, stream>>>(xyz, sq, kidx, kw, wsum);
  k_prep <<<(4*DM*DM)/256, 256, 0, stream>>>(Wq, Wk, Wv, Wd2, Wqt, Wkt, Wvt, Wd2t);
  k_prelu<<<(ROWS*DM)/256, 256, 0, stream>>>(xyz, Wd1, bd1, Prelu);
  k_fc1  <<<ROWS/4, 256, 0, stream>>>(feat, W1, b1, x);
  k_g    <<<ROWS, 256, 0, stream>>>(Prelu, kidx, kw, wsum, g);
  k_gemm <<<dim3(ROWS/128, DM/128), 256, 0, stream>>>(g, Wd2t, bd2, nullptr, wa, nullptr, 0);
  k_gemm <<<dim3(ROWS/128, DM/128), 256, 0, stream>>>(x, Wqt, nullptr, wa, nullptr, qe, 1);
  k_gemm <<<dim3(ROWS/128, DM/128), 256, 0, stream>>>(x, Wkt, nullptr, wa, nullptr, ke, 1);
  k_gemm <<<dim3(ROWS/128, DM/128), 256, 0, stream>>>(x, Wvt, nullptr, wa, nullptr, ve, 1);
  k_vt   <<<dim3(NN/32, DM/32, BB), 256, 0, stream>>>(ve, vt);
  k_attn <<<dim3(NN/64 * BB), 512, 0, stream>>>(qe, ke, vt, attn);
  k_res  <<<ROWS/4, 256, 0, stream>>>(attn, W2, b2, feat, res);
}

// Round 5
// 511.421 us; speedup vs baseline: 1.4608x; 1.0358x over previous
//
#include <hip/hip_runtime.h>

#define BB 8
#define NN 2048
#define DP 64
#define DM 512
#define KNNK 16
#define ROWS (BB*NN)   // 16384

typedef __attribute__((ext_vector_type(8))) short s16x8;
typedef __attribute__((ext_vector_type(4))) short s16x4;
typedef __attribute__((ext_vector_type(4))) float f32x4;

__device__ __forceinline__ float bf2f(short u){
  union { unsigned int i; float f; } v; v.i = ((unsigned int)(unsigned short)u) << 16; return v.f;
}
__device__ __forceinline__ short f2bf(float f){
  union { float f; unsigned int i; } v; v.f = f;
  unsigned int x = v.i;
  return (short)((x + 0x7fffu + ((x >> 16) & 1u)) >> 16);
}

// global -> LDS direct (16B per lane)
__device__ __forceinline__ void gload16(const void* g, void* l){
  __builtin_amdgcn_global_load_lds(
      (const __attribute__((address_space(1))) void*)(__UINTPTR_TYPE__)g,
      (__attribute__((address_space(3))) void*)(__UINTPTR_TYPE__)l, 16, 0, 0);
}

// ---------------- sq = ||xyz||^2 ----------------
__global__ void k_sq(const float* __restrict__ xyz, float* __restrict__ sq){
  int i = blockIdx.x*256 + threadIdx.x;
  if (i < ROWS){
    float x = xyz[3*i], y = xyz[3*i+1], z = xyz[3*i+2];
    sq[i] = x*x + y*y + z*z;
  }
}

// ---------------- exact knn: wave-per-row, dists in 32 VGPRs, zero barriers ----------------
__global__ __launch_bounds__(256) void k_knn(const float* __restrict__ xyz, const float* __restrict__ sq,
        int* __restrict__ kidx, float* __restrict__ kw, float* __restrict__ wsum){
  int row = blockIdx.x*4 + (threadIdx.x >> 6);
  int l = threadIdx.x & 63;
  int b = row >> 11; int i = row & (NN-1);
  const float* xb = xyz + (size_t)b*NN*3;
  const float* sqb = sq + (size_t)b*NN;
  float xi0 = xb[3*i], xi1 = xb[3*i+1], xi2 = xb[3*i+2];
  float sqi = sqb[i];
  float d[32];
  #pragma unroll
  for (int e = 0; e < 32; ++e){
    int j = e*64 + l;
    d[e] = sqi + sqb[j] - 2.0f*(xi0*xb[3*j] + xi1*xb[3*j+1] + xi2*xb[3*j+2]);
  }
  float wacc = 0.f;
  for (int sel = 0; sel < KNNK; ++sel){
    float best = d[0]; int be = 0;
    #pragma unroll
    for (int e = 1; e < 32; ++e){
      bool c = d[e] < best;
      be = c ? e : be;
      best = c ? d[e] : best;
    }
    int bidx = be*64 + l;
    #pragma unroll
    for (int off = 32; off > 0; off >>= 1){
      float ov = __shfl_xor(best, off);
      int   oi = __shfl_xor(bidx, off);
      bool c = (ov < best) || (ov == best && oi < bidx);
      best = c ? ov : best;
      bidx = c ? oi : bidx;
    }
    float wg = 1.0f/(best + 1e-6f);
    wacc += wg;
    if (l == 0){
      kidx[(size_t)row*KNNK + sel] = bidx;
      kw[(size_t)row*KNNK + sel] = wg;
    }
    int pe = bidx >> 6, pl = bidx & 63;
    bool mine = (l == pl);
    #pragma unroll
    for (int e = 0; e < 32; ++e)
      if (e == pe && mine) d[e] = 3.0e38f;
  }
  if (l == 0) wsum[row] = wacc;
}

// ---------------- one-shot prep: transposed bf16 weights + featb ----------------
__global__ void k_prep2(const float* __restrict__ Wq, const float* __restrict__ Wk,
                        const float* __restrict__ Wv, const float* __restrict__ Wd2,
                        const float* __restrict__ W1, const float* __restrict__ W2,
                        const float* __restrict__ feat,
                        short* __restrict__ Wqt, short* __restrict__ Wkt,
                        short* __restrict__ Wvt, short* __restrict__ Wd2t,
                        short* __restrict__ W1t, short* __restrict__ W2t,
                        short* __restrict__ featb){
  int idx = blockIdx.x*256 + threadIdx.x;
  if (idx < 4*DM*DM){
    int m = idx >> 18;
    int r = idx & (DM*DM-1);
    int n = r >> 9, k = r & 511;
    const float* W = (m==0)?Wq:(m==1)?Wk:(m==2)?Wv:Wd2;
    short* Wt = (m==0)?Wqt:(m==1)?Wkt:(m==2)?Wvt:Wd2t;
    Wt[r] = f2bf(W[k*DM + n]);
  } else if (idx < 4*DM*DM + DM*DP){
    int r = idx - 4*DM*DM;
    int n = r >> 6, k = r & 63;
    W1t[r] = f2bf(W1[k*DM + n]);
  } else if (idx < 4*DM*DM + 2*DM*DP){
    int r = idx - 4*DM*DM - DM*DP;
    int n = r >> 9, k = r & 511;
    W2t[r] = f2bf(W2[k*DP + n]);
  } else {
    int r = idx - 4*DM*DM - 2*DM*DP;
    featb[r] = f2bf(feat[r]);
  }
}

// ---------------- Prelu[row][d] = relu(xyz@Wd1 + bd1), bf16 ----------------
__global__ void k_prelu(const float* __restrict__ xyz, const float* __restrict__ Wd1,
                        const float* __restrict__ bd1, short* __restrict__ Prelu){
  int idx = blockIdx.x*256 + threadIdx.x;
  int row = idx >> 9; int d = idx & (DM-1);
  float x0 = xyz[3*row], x1 = xyz[3*row+1], x2 = xyz[3*row+2];
  float v = x0*Wd1[d] + x1*Wd1[DM + d] + x2*Wd1[2*DM + d] + bd1[d];
  Prelu[idx] = f2bf(fmaxf(v, 0.f));
}

// ---------------- g = (sum_j w_j * Prelu[idx_j]) / wsum, bf16, vectorized ----------------
__global__ __launch_bounds__(256) void k_g(const short* __restrict__ Prelu, const int* __restrict__ kidx,
                   const float* __restrict__ kw, const float* __restrict__ wsum, short* __restrict__ g){
  int p = blockIdx.x*4 + (threadIdx.x>>6);
  int c8 = (threadIdx.x&63)*8;
  int b = p >> 11;
  const short* Pb = Prelu + (size_t)b*NN*DM;
  int jj[KNNK]; float wj[KNNK];
  #pragma unroll
  for (int j = 0; j < KNNK; ++j){
    jj[j] = kidx[(size_t)p*KNNK + j];
    wj[j] = kw[(size_t)p*KNNK + j];
  }
  float acc[8] = {0,0,0,0,0,0,0,0};
  #pragma unroll
  for (int j = 0; j < KNNK; ++j){
    s16x8 v = *(const s16x8*)&Pb[(size_t)jj[j]*DM + c8];
    float w = wj[j];
    #pragma unroll
    for (int e=0;e<8;++e) acc[e] += w*bf2f(v[e]);
  }
  float inv = 1.0f/wsum[p];
  s16x8 o;
  #pragma unroll
  for (int e=0;e<8;++e) o[e] = f2bf(acc[e]*inv);
  *(s16x8*)&g[(size_t)p*DM + c8] = o;
}

// ---------------- bf16 MFMA GEMM template: C[M,512] = A[M,KD] @ Bt[512][KD]^T ----------------
// MODE 0: outb = bf16(acc + bias[col]);  MODE 1: outb = bf16(acc + bf2f(addb[row*DM+col]))
template<int KD, int MODE>
__global__ __launch_bounds__(256) void k_gemm(const short* __restrict__ A, const short* __restrict__ Bt,
       const float* __restrict__ bias, const short* __restrict__ addb, short* __restrict__ outb){
  __shared__ short As[128*32];
  __shared__ short Bs[128*32];
  int t = threadIdx.x;
  size_t i0 = (size_t)blockIdx.x*128, n0 = (size_t)blockIdx.y*128;
  int w = t >> 6, l = t & 63, la = l & 15, lg = l >> 4;
  int wr = w >> 1, wc = w & 1;
  f32x4 acc[4][4];
  #pragma unroll
  for (int h=0;h<4;++h)
    #pragma unroll
    for (int c=0;c<4;++c) acc[h][c] = (f32x4){0.f,0.f,0.f,0.f};
  int srow = t >> 2; int sk8 = (t & 3) * 8;
  const short* Ab  = A  + (i0 + srow)*KD + sk8;
  const short* Ab2 = A  + (i0 + 64 + srow)*KD + sk8;
  const short* Bb  = Bt + (n0 + srow)*KD + sk8;
  const short* Bb2 = Bt + (n0 + 64 + srow)*KD + sk8;
  short* Asd  = &As[t*8];      short* Asd2 = &As[2048 + t*8];
  short* Bsd  = &Bs[t*8];      short* Bsd2 = &Bs[2048 + t*8];
  for (int k0 = 0; k0 < KD; k0 += 32){
    gload16(Ab  + k0, Asd);
    gload16(Ab2 + k0, Asd2);
    gload16(Bb  + k0, Bsd);
    gload16(Bb2 + k0, Bsd2);
    __syncthreads();
    s16x8 af[4], bg[4];
    #pragma unroll
    for (int h=0;h<4;++h) af[h] = *(const s16x8*)&As[(wr*64 + h*16 + la)*32 + lg*8];
    #pragma unroll
    for (int c=0;c<4;++c) bg[c] = *(const s16x8*)&Bs[(wc*64 + c*16 + la)*32 + lg*8];
    #pragma unroll
    for (int h=0;h<4;++h)
      #pragma unroll
      for (int c=0;c<4;++c)
        acc[h][c] = __builtin_amdgcn_mfma_f32_16x16x32_bf16(af[h], bg[c], acc[h][c], 0, 0, 0);
    __syncthreads();
  }
  #pragma unroll
  for (int h=0;h<4;++h){
    #pragma unroll
    for (int c=0;c<4;++c){
      size_t col = n0 + wc*64 + c*16 + la;
      #pragma unroll
      for (int r=0;r<4;++r){
        size_t row = i0 + wr*64 + h*16 + lg*4 + r;
        float v = acc[h][c][r];
        if (MODE == 0) outb[row*DM + col] = f2bf(v + bias[col]);
        else           outb[row*DM + col] = f2bf(v + bf2f(addb[row*DM + col]));
      }
    }
  }
}

// ---------------- transpose ve -> vt[b][d][j] ----------------
__global__ __launch_bounds__(256) void k_vt(const short* __restrict__ ve, short* __restrict__ vt){
  int j0 = blockIdx.x*32, d0 = blockIdx.y*32, b = blockIdx.z;
  __shared__ short tile[32][36];
  int t = threadIdx.x;
  int r = t >> 3, c4 = (t & 7)*4;
  const short* vb = ve + (size_t)b*NN*DM;
  *(s16x4*)&tile[r][c4] = *(const s16x4*)&vb[(size_t)(j0+r)*DM + d0 + c4];
  __syncthreads();
  s16x4 o;
  #pragma unroll
  for (int e=0;e<4;++e) o[e] = tile[c4+e][r];
  short* ob = vt + (size_t)b*DM*NN;
  *(s16x4*)&ob[(size_t)(d0+r)*NN + j0 + c4] = o;
}

// ---------------- attention: 32 q-rows/block, 8 waves, j-split scores, d-split PV ----------------
__global__ __launch_bounds__(512) void k_attn(const short* __restrict__ qe, const short* __restrict__ ke,
        const short* __restrict__ vt, float* __restrict__ attn, short* __restrict__ attb){
  int bid = blockIdx.x;
  int b  = bid & 7;            // batch pinned per XCD
  int i0 = (bid >> 3) * 32;
  int t = threadIdx.x, w = t >> 6, l = t & 63, la = l & 15, lg = l >> 4;
  __shared__ short qlds[32*520];   // 33.3 KB
  __shared__ short plds[32*256];   // 16.4 KB, XOR-swizzled by ((q&7)<<4)
  __shared__ float lsred[8][32];
  const short* qb = qe + (size_t)b*NN*DM;
  const short* kb = ke + (size_t)b*NN*DM;
  const short* vb = vt + (size_t)b*DM*NN;

  #pragma unroll
  for (int it = 0; it < 4; ++it){
    int idx = it*512 + t;
    int r = idx >> 6, ch = idx & 63;
    *(s16x8*)&qlds[r*520 + ch*8] = *(const s16x8*)&qb[(size_t)(i0+r)*DM + ch*8];
  }
  f32x4 Oa[2][4];
  float plsum[8];
  #pragma unroll
  for (int qh=0;qh<2;++qh){
    #pragma unroll
    for (int dt=0;dt<4;++dt) Oa[qh][dt] = (f32x4){0.f,0.f,0.f,0.f};
    #pragma unroll
    for (int r=0;r<4;++r) plsum[qh*4+r] = 0.f;
  }
  __syncthreads();
  const float scale = 0.044194173824159216f;  // 1/sqrt(512)

  for (int jt = 0; jt < 8; ++jt){
    int j0 = jt*256;
    int jw = j0 + w*32;
    f32x4 sacc[2][2];
    #pragma unroll
    for (int qh=0;qh<2;++qh){ sacc[qh][0] = (f32x4){0.f,0.f,0.f,0.f}; sacc[qh][1] = (f32x4){0.f,0.f,0.f,0.f}; }
    #pragma unroll
    for (int ks = 0; ks < 16; ++ks){
      int kk = ks*32;
      s16x8 b0 = *(const s16x8*)&kb[(size_t)(jw + la)*DM + kk + lg*8];
      s16x8 b1 = *(const s16x8*)&kb[(size_t)(jw + 16 + la)*DM + kk + lg*8];
      __builtin_amdgcn_s_setprio(1);
      #pragma unroll
      for (int qh = 0; qh < 2; ++qh){
        s16x8 a = *(const s16x8*)&qlds[(qh*16 + la)*520 + kk + lg*8];
        sacc[qh][0] = __builtin_amdgcn_mfma_f32_16x16x32_bf16(a, b0, sacc[qh][0], 0,0,0);
        sacc[qh][1] = __builtin_amdgcn_mfma_f32_16x16x32_bf16(a, b1, sacc[qh][1], 0,0,0);
      }
      __builtin_amdgcn_s_setprio(0);
    }
    #pragma unroll
    for (int qh = 0; qh < 2; ++qh){
      #pragma unroll
      for (int c = 0; c < 2; ++c){
        int jloc = w*32 + c*16 + la;
        #pragma unroll
        for (int r = 0; r < 4; ++r){
          int q = qh*16 + lg*4 + r;
          float p = __expf(sacc[qh][c][r]*scale);
          plsum[qh*4+r] += p;
          int byt = (q*512 + jloc*2) ^ ((q&7)<<4);
          *(short*)((char*)plds + byt) = f2bf(p);
        }
      }
    }
    __syncthreads();
    int d0 = w*64;
    #pragma unroll
    for (int js = 0; js < 8; ++js){
      s16x8 pa[2];
      #pragma unroll
      for (int qh = 0; qh < 2; ++qh){
        int byt = ((qh*16 + la)*512 + js*64 + lg*16) ^ ((la&7)<<4);
        pa[qh] = *(const s16x8*)((const char*)plds + byt);
      }
      __builtin_amdgcn_s_setprio(1);
      #pragma unroll
      for (int dt = 0; dt < 4; ++dt){
        s16x8 bv = *(const s16x8*)&vb[(size_t)(d0 + dt*16 + la)*NN + j0 + js*32 + lg*8];
        #pragma unroll
        for (int qh = 0; qh < 2; ++qh)
          Oa[qh][dt] = __builtin_amdgcn_mfma_f32_16x16x32_bf16(pa[qh], bv, Oa[qh][dt], 0,0,0);
      }
      __builtin_amdgcn_s_setprio(0);
    }
    __syncthreads();
  }
  #pragma unroll
  for (int m = 1; m < 16; m <<= 1){
    #pragma unroll
    for (int i = 0; i < 8; ++i) plsum[i] += __shfl_xor(plsum[i], m);
  }
  if (la == 0){
    #pragma unroll
    for (int qh = 0; qh < 2; ++qh)
      #pragma unroll
      for (int r = 0; r < 4; ++r)
        lsred[w][qh*16 + lg*4 + r] = plsum[qh*4+r];
  }
  __syncthreads();
  if (t < 32){
    float s = 0.f;
    #pragma unroll
    for (int ww = 0; ww < 8; ++ww) s += lsred[ww][t];
    lsred[0][t] = 1.0f/s;
  }
  __syncthreads();
  float* ab = attn + (size_t)b*NN*DM;
  short* abb = attb;
  int d0 = w*64;
  #pragma unroll
  for (int qh = 0; qh < 2; ++qh){
    #pragma unroll
    for (int r = 0; r < 4; ++r){
      int q = qh*16 + lg*4 + r;
      float linv = lsred[0][q];
      #pragma unroll
      for (int dt = 0; dt < 4; ++dt){
        float val = Oa[qh][dt][r]*linv;
        size_t off = (size_t)(i0 + q)*DM + d0 + dt*16 + la;
        ab[off] = val;
        abb[((size_t)b*NN*DM) + off] = f2bf(val);
      }
    }
  }
}

// ---------------- res = attb@W2t^T + b2 + feat (MFMA, N=64) ----------------
__global__ __launch_bounds__(256) void k_res(const short* __restrict__ attb, const short* __restrict__ W2t,
       const float* __restrict__ b2, const float* __restrict__ feat, float* __restrict__ res){
  __shared__ short As[128*32];
  __shared__ short Bs[64*32];
  int t = threadIdx.x;
  size_t i0 = (size_t)blockIdx.x*128;
  int w = t >> 6, l = t & 63, la = l & 15, lg = l >> 4;
  f32x4 acc[2][4];
  #pragma unroll
  for (int h=0;h<2;++h)
    #pragma unroll
    for (int c=0;c<4;++c) acc[h][c] = (f32x4){0.f,0.f,0.f,0.f};
  int ar0 = t >> 2;         // chunk t: row t>>2, off (t&3)*8
  int ao0 = (t & 3) * 8;
  int ar1 = (t + 256) >> 2;
  for (int k0 = 0; k0 < DM; k0 += 32){
    gload16(attb + (i0 + ar0)*DM + k0 + ao0, &As[t*8]);
    gload16(attb + (i0 + ar1)*DM + k0 + ao0, &As[2048 + t*8]);
    gload16(W2t + (size_t)(t>>2)*DM + k0 + (t&3)*8, &Bs[t*8]);   // all 256 lanes: 64 rows x 32
    __syncthreads();
    s16x8 af[2], bg[4];
    #pragma unroll
    for (int h=0;h<2;++h) af[h] = *(const s16x8*)&As[(w*32 + h*16 + la)*32 + lg*8];
    #pragma unroll
    for (int c=0;c<4;++c) bg[c] = *(const s16x8*)&Bs[(c*16 + la)*32 + lg*8];
    #pragma unroll
    for (int h=0;h<2;++h)
      #pragma unroll
      for (int c=0;c<4;++c)
        acc[h][c] = __builtin_amdgcn_mfma_f32_16x16x32_bf16(af[h], bg[c], acc[h][c], 0, 0, 0);
    __syncthreads();
  }
  #pragma unroll
  for (int h=0;h<2;++h){
    #pragma unroll
    for (int c=0;c<4;++c){
      int col = c*16 + la;
      #pragma unroll
      for (int r=0;r<4;++r){
        size_t row = i0 + w*32 + h*16 + lg*4 + r;
        res[row*DP + col] = acc[h][c][r] + b2[col] + feat[row*DP + col];
      }
    }
  }
}

extern "C" void kernel_launch(void* const* d_in, const int* in_sizes, int n_in,
                              void* d_out, int out_size, void* d_ws, size_t ws_size,
                              hipStream_t stream){
  const float* xyz  = (const float*)d_in[0];
  const float* feat = (const float*)d_in[1];
  const float* W1   = (const float*)d_in[2];
  const float* b1   = (const float*)d_in[3];
  const float* W2   = (const float*)d_in[4];
  const float* b2   = (const float*)d_in[5];
  const float* Wd1  = (const float*)d_in[6];
  const float* bd1  = (const float*)d_in[7];
  const float* Wd2  = (const float*)d_in[8];
  const float* bd2  = (const float*)d_in[9];
  const float* Wq   = (const float*)d_in[10];
  const float* Wk   = (const float*)d_in[11];
  const float* Wv   = (const float*)d_in[12];

  char* ws = (char*)d_ws;                        // ~95 MB
  float* sq    = (float*)(ws + (0ull<<20));
  int*   kidx  = (int*)  (ws + (1ull<<20));
  float* kw    = (float*)(ws + (2ull<<20));
  float* wsum  = (float*)(ws + (3ull<<20));
  short* Wqt   = (short*)(ws + (4ull<<20));
  short* Wkt   = Wqt + (size_t)DM*DM;
  short* Wvt   = Wkt + (size_t)DM*DM;
  short* Wd2t  = Wvt + (size_t)DM*DM;
  short* W1t   = (short*)(ws + (6ull<<20));
  short* W2t   = (short*)(ws + (7ull<<20));
  short* featb = (short*)(ws + (8ull<<20));
  short* Prelu = (short*)(ws + (10ull<<20));     // reused as qe
  short* g     = (short*)(ws + (27ull<<20));     // reused as ke
  short* x     = (short*)(ws + (44ull<<20));     // reused as vt
  short* wab   = (short*)(ws + (61ull<<20));     // reused as attb
  short* ve    = (short*)(ws + (78ull<<20));
  short* qe = Prelu; short* ke = g; short* vt = x; short* attb = wab;

  float* res  = (float*)d_out;
  float* attn = (float*)d_out + (size_t)ROWS*DP;

  k_sq   <<<ROWS/256, 256, 0, stream>>>(xyz, sq);
  k_knn  <<<ROWS/4, 256, 0, stream>>>(xyz, sq, kidx, kw, wsum);
  k_prep2<<<(4*DM*DM + 2*DM*DP + ROWS*DP)/256, 256, 0, stream>>>(
           Wq, Wk, Wv, Wd2, W1, W2, feat, Wqt, Wkt, Wvt, Wd2t, W1t, W2t, featb);
  k_prelu<<<(ROWS*DM)/256, 256, 0, stream>>>(xyz, Wd1, bd1, Prelu);
  k_g    <<<ROWS/4, 256, 0, stream>>>(Prelu, kidx, kw, wsum, g);
  k_gemm<DP,0>  <<<dim3(ROWS/128, DM/128), 256, 0, stream>>>(featb, W1t, b1, nullptr, x);
  k_gemm<DM,0>  <<<dim3(ROWS/128, DM/128), 256, 0, stream>>>(g, Wd2t, bd2, nullptr, wab);
  k_gemm<DM,1>  <<<dim3(ROWS/128, DM/128), 256, 0, stream>>>(x, Wqt, nullptr, wab, qe);
  k_gemm<DM,1>  <<<dim3(ROWS/128, DM/128), 256, 0, stream>>>(x, Wkt, nullptr, wab, ke);
  k_gemm<DM,1>  <<<dim3(ROWS/128, DM/128), 256, 0, stream>>>(x, Wvt, nullptr, wab, ve);
  k_vt   <<<dim3(NN/32, DM/32, BB), 256, 0, stream>>>(ve, vt);
  k_attn <<<dim3((NN/32) * BB), 512, 0, stream>>>(qe, ke, vt, attn, attb);
  k_res  <<<ROWS/128, 256, 0, stream>>>(attb, W2t, b2, feat, res);
}

// Round 6
// 381.775 us; speedup vs baseline: 1.9568x; 1.3396x over previous
//
#include <hip/hip_runtime.h>

#define BB 8
#define NN 2048
#define DP 64
#define DM 512
#define KNNK 16
#define ROWS (BB*NN)   // 16384

typedef __attribute__((ext_vector_type(8))) short s16x8;
typedef __attribute__((ext_vector_type(4))) short s16x4;
typedef __attribute__((ext_vector_type(4))) float f32x4;

__device__ __forceinline__ float bf2f(short u){
  union { unsigned int i; float f; } v; v.i = ((unsigned int)(unsigned short)u) << 16; return v.f;
}
__device__ __forceinline__ short f2bf(float f){
  union { float f; unsigned int i; } v; v.f = f;
  unsigned int x = v.i;
  return (short)((x + 0x7fffu + ((x >> 16) & 1u)) >> 16);
}

// global -> LDS direct (16B per lane)
__device__ __forceinline__ void gload16(const void* g, void* l){
  __builtin_amdgcn_global_load_lds(
      (const __attribute__((address_space(1))) void*)(__UINTPTR_TYPE__)g,
      (__attribute__((address_space(3))) void*)(__UINTPTR_TYPE__)l, 16, 0, 0);
}

// ---------------- sq = ||xyz||^2 ----------------
__global__ void k_sq(const float* __restrict__ xyz, float* __restrict__ sq){
  int i = blockIdx.x*256 + threadIdx.x;
  if (i < ROWS){
    float x = xyz[3*i], y = xyz[3*i+1], z = xyz[3*i+2];
    sq[i] = x*x + y*y + z*z;
  }
}

// ---------------- exact knn: wave-per-row, dists in 32 VGPRs, zero barriers ----------------
__global__ __launch_bounds__(256) void k_knn(const float* __restrict__ xyz, const float* __restrict__ sq,
        int* __restrict__ kidx, float* __restrict__ kw, float* __restrict__ wsum){
  int row = blockIdx.x*4 + (threadIdx.x >> 6);
  int l = threadIdx.x & 63;
  int b = row >> 11; int i = row & (NN-1);
  const float* xb = xyz + (size_t)b*NN*3;
  const float* sqb = sq + (size_t)b*NN;
  float xi0 = xb[3*i], xi1 = xb[3*i+1], xi2 = xb[3*i+2];
  float sqi = sqb[i];
  float d[32];
  #pragma unroll
  for (int e = 0; e < 32; ++e){
    int j = e*64 + l;
    d[e] = sqi + sqb[j] - 2.0f*(xi0*xb[3*j] + xi1*xb[3*j+1] + xi2*xb[3*j+2]);
  }
  float wacc = 0.f;
  for (int sel = 0; sel < KNNK; ++sel){
    float best = d[0]; int be = 0;
    #pragma unroll
    for (int e = 1; e < 32; ++e){
      bool c = d[e] < best;
      be = c ? e : be;
      best = c ? d[e] : best;
    }
    int bidx = be*64 + l;
    #pragma unroll
    for (int off = 32; off > 0; off >>= 1){
      float ov = __shfl_xor(best, off);
      int   oi = __shfl_xor(bidx, off);
      bool c = (ov < best) || (ov == best && oi < bidx);
      best = c ? ov : best;
      bidx = c ? oi : bidx;
    }
    float wg = 1.0f/(best + 1e-6f);
    wacc += wg;
    if (l == 0){
      kidx[(size_t)row*KNNK + sel] = bidx;
      kw[(size_t)row*KNNK + sel] = wg;
    }
    int pe = bidx >> 6, pl = bidx & 63;
    bool mine = (l == pl);
    #pragma unroll
    for (int e = 0; e < 32; ++e)
      if (e == pe && mine) d[e] = 3.0e38f;
  }
  if (l == 0) wsum[row] = wacc;
}

// ---------------- one-shot prep: transposed bf16 weights + featb ----------------
__global__ void k_prep2(const float* __restrict__ Wq, const float* __restrict__ Wk,
                        const float* __restrict__ Wv, const float* __restrict__ Wd2,
                        const float* __restrict__ W1, const float* __restrict__ W2,
                        const float* __restrict__ feat,
                        short* __restrict__ Wqt, short* __restrict__ Wkt,
                        short* __restrict__ Wvt, short* __restrict__ Wd2t,
                        short* __restrict__ W1t, short* __restrict__ W2t,
                        short* __restrict__ featb){
  int idx = blockIdx.x*256 + threadIdx.x;
  if (idx < 4*DM*DM){
    int m = idx >> 18;
    int r = idx & (DM*DM-1);
    int n = r >> 9, k = r & 511;
    const float* W = (m==0)?Wq:(m==1)?Wk:(m==2)?Wv:Wd2;
    short* Wt = (m==0)?Wqt:(m==1)?Wkt:(m==2)?Wvt:Wd2t;
    Wt[r] = f2bf(W[k*DM + n]);
  } else if (idx < 4*DM*DM + DM*DP){
    int r = idx - 4*DM*DM;
    int n = r >> 6, k = r & 63;
    W1t[r] = f2bf(W1[k*DM + n]);
  } else if (idx < 4*DM*DM + 2*DM*DP){
    int r = idx - 4*DM*DM - DM*DP;
    int n = r >> 9, k = r & 511;
    W2t[r] = f2bf(W2[k*DP + n]);
  } else {
    int r = idx - 4*DM*DM - 2*DM*DP;
    featb[r] = f2bf(feat[r]);
  }
}

// ---------------- Prelu[row][d] = relu(xyz@Wd1 + bd1), bf16 ----------------
__global__ void k_prelu(const float* __restrict__ xyz, const float* __restrict__ Wd1,
                        const float* __restrict__ bd1, short* __restrict__ Prelu){
  int idx = blockIdx.x*256 + threadIdx.x;
  int row = idx >> 9; int d = idx & (DM-1);
  float x0 = xyz[3*row], x1 = xyz[3*row+1], x2 = xyz[3*row+2];
  float v = x0*Wd1[d] + x1*Wd1[DM + d] + x2*Wd1[2*DM + d] + bd1[d];
  Prelu[idx] = f2bf(fmaxf(v, 0.f));
}

// ---------------- g = (sum_j w_j * Prelu[idx_j]) / wsum, bf16, batch-pinned ----------------
__global__ __launch_bounds__(256) void k_g(const short* __restrict__ Prelu, const int* __restrict__ kidx,
                   const float* __restrict__ kw, const float* __restrict__ wsum, short* __restrict__ g){
  int bid = blockIdx.x;
  int p = ((bid&7)<<11) + ((bid>>3)<<2) + (threadIdx.x>>6);   // batch = bid&7 (XCD-pinned)
  int c8 = (threadIdx.x&63)*8;
  int b = p >> 11;
  const short* Pb = Prelu + (size_t)b*NN*DM;
  int jj[KNNK]; float wj[KNNK];
  #pragma unroll
  for (int j = 0; j < KNNK; ++j){
    jj[j] = kidx[(size_t)p*KNNK + j];
    wj[j] = kw[(size_t)p*KNNK + j];
  }
  float acc[8] = {0,0,0,0,0,0,0,0};
  #pragma unroll
  for (int j = 0; j < KNNK; ++j){
    s16x8 v = *(const s16x8*)&Pb[(size_t)jj[j]*DM + c8];
    float w = wj[j];
    #pragma unroll
    for (int e=0;e<8;++e) acc[e] += w*bf2f(v[e]);
  }
  float inv = 1.0f/wsum[p];
  s16x8 o;
  #pragma unroll
  for (int e=0;e<8;++e) o[e] = f2bf(acc[e]*inv);
  *(s16x8*)&g[(size_t)p*DM + c8] = o;
}

// ---------------- bf16 MFMA GEMM template: C[M,512] = A[M,KD] @ Bt[512][KD]^T ----------------
template<int KD, int MODE>
__global__ __launch_bounds__(256) void k_gemm(const short* __restrict__ A, const short* __restrict__ Bt,
       const float* __restrict__ bias, const short* __restrict__ addb, short* __restrict__ outb){
  __shared__ short As[128*32];
  __shared__ short Bs[128*32];
  int t = threadIdx.x;
  size_t i0 = (size_t)blockIdx.x*128, n0 = (size_t)blockIdx.y*128;
  int w = t >> 6, l = t & 63, la = l & 15, lg = l >> 4;
  int wr = w >> 1, wc = w & 1;
  f32x4 acc[4][4];
  #pragma unroll
  for (int h=0;h<4;++h)
    #pragma unroll
    for (int c=0;c<4;++c) acc[h][c] = (f32x4){0.f,0.f,0.f,0.f};
  int srow = t >> 2; int sk8 = (t & 3) * 8;
  const short* Ab  = A  + (i0 + srow)*KD + sk8;
  const short* Ab2 = A  + (i0 + 64 + srow)*KD + sk8;
  const short* Bb  = Bt + (n0 + srow)*KD + sk8;
  const short* Bb2 = Bt + (n0 + 64 + srow)*KD + sk8;
  short* Asd  = &As[t*8];      short* Asd2 = &As[2048 + t*8];
  short* Bsd  = &Bs[t*8];      short* Bsd2 = &Bs[2048 + t*8];
  for (int k0 = 0; k0 < KD; k0 += 32){
    gload16(Ab  + k0, Asd);
    gload16(Ab2 + k0, Asd2);
    gload16(Bb  + k0, Bsd);
    gload16(Bb2 + k0, Bsd2);
    __syncthreads();
    s16x8 af[4], bg[4];
    #pragma unroll
    for (int h=0;h<4;++h) af[h] = *(const s16x8*)&As[(wr*64 + h*16 + la)*32 + lg*8];
    #pragma unroll
    for (int c=0;c<4;++c) bg[c] = *(const s16x8*)&Bs[(wc*64 + c*16 + la)*32 + lg*8];
    #pragma unroll
    for (int h=0;h<4;++h)
      #pragma unroll
      for (int c=0;c<4;++c)
        acc[h][c] = __builtin_amdgcn_mfma_f32_16x16x32_bf16(af[h], bg[c], acc[h][c], 0, 0, 0);
    __syncthreads();
  }
  #pragma unroll
  for (int h=0;h<4;++h){
    #pragma unroll
    for (int c=0;c<4;++c){
      size_t col = n0 + wc*64 + c*16 + la;
      #pragma unroll
      for (int r=0;r<4;++r){
        size_t row = i0 + wr*64 + h*16 + lg*4 + r;
        float v = acc[h][c][r];
        if (MODE == 0) outb[row*DM + col] = f2bf(v + bias[col]);
        else           outb[row*DM + col] = f2bf(v + bf2f(addb[row*DM + col]));
      }
    }
  }
}

// ---------------- transpose ve -> vt[b][d][j] ----------------
__global__ __launch_bounds__(256) void k_vt(const short* __restrict__ ve, short* __restrict__ vt){
  int j0 = blockIdx.x*32, d0 = blockIdx.y*32, b = blockIdx.z;
  __shared__ short tile[32][36];
  int t = threadIdx.x;
  int r = t >> 3, c4 = (t & 7)*4;
  const short* vb = ve + (size_t)b*NN*DM;
  *(s16x4*)&tile[r][c4] = *(const s16x4*)&vb[(size_t)(j0+r)*DM + d0 + c4];
  __syncthreads();
  s16x4 o;
  #pragma unroll
  for (int e=0;e<4;++e) o[e] = tile[c4+e][r];
  short* ob = vt + (size_t)b*DM*NN;
  *(s16x4*)&ob[(size_t)(d0+r)*NN + j0 + c4] = o;
}

// ---------------- S-GEMM + exp: P[b][i][jlocal] = exp(scale * qe_i . ke_(joff+j)) ----------------
// 128x128 tile, per-batch (batch = bid&7, XCD-pinned). Row-sum partials to lsum_part (no atomics).
__global__ __launch_bounds__(256) void k_sexp(const short* __restrict__ qe, const short* __restrict__ ke,
       int joff, short* __restrict__ pbuf, float* __restrict__ lsum_part, int slot0){
  __shared__ short As[128*32];
  __shared__ short Bs[128*32];
  int bid = blockIdx.x;
  int b = bid & 7;
  int r2 = bid >> 3;                 // 0..127
  int ti = r2 & 15, tj = r2 >> 4;    // i-tile 0..15, j-tile 0..7
  size_t i0 = (size_t)ti*128;
  size_t j0 = (size_t)tj*128;        // local to this pass
  const short* A  = qe + (size_t)b*NN*DM;
  const short* Bt = ke + (size_t)b*NN*DM + (size_t)joff*DM;
  int t = threadIdx.x;
  int w = t >> 6, l = t & 63, la = l & 15, lg = l >> 4;
  int wr = w >> 1, wc = w & 1;
  f32x4 acc[4][4];
  #pragma unroll
  for (int h=0;h<4;++h)
    #pragma unroll
    for (int c=0;c<4;++c) acc[h][c] = (f32x4){0.f,0.f,0.f,0.f};
  int srow = t >> 2; int sk8 = (t & 3) * 8;
  const short* Ab  = A  + (i0 + srow)*DM + sk8;
  const short* Ab2 = A  + (i0 + 64 + srow)*DM + sk8;
  const short* Bb  = Bt + (j0 + srow)*DM + sk8;
  const short* Bb2 = Bt + (j0 + 64 + srow)*DM + sk8;
  short* Asd  = &As[t*8];      short* Asd2 = &As[2048 + t*8];
  short* Bsd  = &Bs[t*8];      short* Bsd2 = &Bs[2048 + t*8];
  for (int k0 = 0; k0 < DM; k0 += 32){
    gload16(Ab  + k0, Asd);
    gload16(Ab2 + k0, Asd2);
    gload16(Bb  + k0, Bsd);
    gload16(Bb2 + k0, Bsd2);
    __syncthreads();
    s16x8 af[4], bg[4];
    #pragma unroll
    for (int h=0;h<4;++h) af[h] = *(const s16x8*)&As[(wr*64 + h*16 + la)*32 + lg*8];
    #pragma unroll
    for (int c=0;c<4;++c) bg[c] = *(const s16x8*)&Bs[(wc*64 + c*16 + la)*32 + lg*8];
    #pragma unroll
    for (int h=0;h<4;++h)
      #pragma unroll
      for (int c=0;c<4;++c)
        acc[h][c] = __builtin_amdgcn_mfma_f32_16x16x32_bf16(af[h], bg[c], acc[h][c], 0, 0, 0);
    __syncthreads();
  }
  const float scale = 0.044194173824159216f;  // 1/sqrt(512)
  short* pb = pbuf + (size_t)b*NN*1024;
  float rsum[4][4];
  #pragma unroll
  for (int h=0;h<4;++h)
    #pragma unroll
    for (int r=0;r<4;++r) rsum[h][r] = 0.f;
  #pragma unroll
  for (int h=0;h<4;++h){
    #pragma unroll
    for (int c=0;c<4;++c){
      size_t col = j0 + wc*64 + c*16 + la;
      #pragma unroll
      for (int r=0;r<4;++r){
        size_t row = i0 + wr*64 + h*16 + lg*4 + r;
        float p = __expf(acc[h][c][r]*scale);
        rsum[h][r] += p;
        pb[row*1024 + col] = f2bf(p);
      }
    }
  }
  // reduce row partials over the 16 la-lanes (masks <16 stay within group)
  #pragma unroll
  for (int m = 1; m < 16; m <<= 1){
    #pragma unroll
    for (int h=0;h<4;++h)
      #pragma unroll
      for (int r=0;r<4;++r) rsum[h][r] += __shfl_xor(rsum[h][r], m);
  }
  if (la == 0){
    float* lp = lsum_part + (size_t)((slot0 + tj)*2 + wc)*ROWS + (size_t)b*NN;
    #pragma unroll
    for (int h=0;h<4;++h)
      #pragma unroll
      for (int r=0;r<4;++r)
        lp[i0 + wr*64 + h*16 + lg*4 + r] = rsum[h][r];
  }
}

// ---------------- linv = 1 / sum over 32 partial slots ----------------
__global__ void k_lsum(const float* __restrict__ lsum_part, float* __restrict__ linv){
  int g = blockIdx.x*256 + threadIdx.x;
  float s = 0.f;
  #pragma unroll
  for (int i = 0; i < 32; ++i) s += lsum_part[(size_t)i*ROWS + g];
  linv[g] = 1.0f/s;
}

// ---------------- PV GEMM: O = P @ V (vt is [b][d][j]) ----------------
// FINAL=0: attn = acc (raw). FINAL=1: v=(attn+acc)*linv; attn=v; attb=bf16(v).
template<int FINAL>
__global__ __launch_bounds__(256) void k_pv(const short* __restrict__ pbuf, const short* __restrict__ vt,
        int joff, const float* __restrict__ linv, float* __restrict__ attn, short* __restrict__ attb){
  __shared__ short As[128*32];
  __shared__ short Bs[128*32];
  int bid = blockIdx.x;
  int b = bid & 7;
  int r2 = bid >> 3;                 // 0..63
  int ti = r2 & 15, tn = r2 >> 4;    // i-tile 0..15, d-tile 0..3
  size_t i0 = (size_t)ti*128;
  size_t n0 = (size_t)tn*128;
  const short* A  = pbuf + (size_t)b*NN*1024;
  const short* Bt = vt + (size_t)b*DM*NN + joff;
  int t = threadIdx.x;
  int w = t >> 6, l = t & 63, la = l & 15, lg = l >> 4;
  int wr = w >> 1, wc = w & 1;
  f32x4 acc[4][4];
  #pragma unroll
  for (int h=0;h<4;++h)
    #pragma unroll
    for (int c=0;c<4;++c) acc[h][c] = (f32x4){0.f,0.f,0.f,0.f};
  int srow = t >> 2; int sk8 = (t & 3) * 8;
  const short* Ab  = A  + (i0 + srow)*1024 + sk8;
  const short* Ab2 = A  + (i0 + 64 + srow)*1024 + sk8;
  const short* Bb  = Bt + (n0 + srow)*NN + sk8;
  const short* Bb2 = Bt + (n0 + 64 + srow)*NN + sk8;
  short* Asd  = &As[t*8];      short* Asd2 = &As[2048 + t*8];
  short* Bsd  = &Bs[t*8];      short* Bsd2 = &Bs[2048 + t*8];
  for (int k0 = 0; k0 < 1024; k0 += 32){
    gload16(Ab  + k0, Asd);
    gload16(Ab2 + k0, Asd2);
    gload16(Bb  + k0, Bsd);
    gload16(Bb2 + k0, Bsd2);
    __syncthreads();
    s16x8 af[4], bg[4];
    #pragma unroll
    for (int h=0;h<4;++h) af[h] = *(const s16x8*)&As[(wr*64 + h*16 + la)*32 + lg*8];
    #pragma unroll
    for (int c=0;c<4;++c) bg[c] = *(const s16x8*)&Bs[(wc*64 + c*16 + la)*32 + lg*8];
    #pragma unroll
    for (int h=0;h<4;++h)
      #pragma unroll
      for (int c=0;c<4;++c)
        acc[h][c] = __builtin_amdgcn_mfma_f32_16x16x32_bf16(af[h], bg[c], acc[h][c], 0, 0, 0);
    __syncthreads();
  }
  #pragma unroll
  for (int h=0;h<4;++h){
    #pragma unroll
    for (int c=0;c<4;++c){
      size_t col = n0 + wc*64 + c*16 + la;
      #pragma unroll
      for (int r=0;r<4;++r){
        size_t row = i0 + wr*64 + h*16 + lg*4 + r;
        size_t off = (size_t)b*NN*DM + row*DM + col;
        if (FINAL == 0){
          attn[off] = acc[h][c][r];
        } else {
          float v = (attn[off] + acc[h][c][r]) * linv[(size_t)b*NN + row];
          attn[off] = v;
          attb[off] = f2bf(v);
        }
      }
    }
  }
}

// ---------------- res = attb@W2t^T + b2 + feat (MFMA, N=64) ----------------
__global__ __launch_bounds__(256) void k_res(const short* __restrict__ attb, const short* __restrict__ W2t,
       const float* __restrict__ b2, const float* __restrict__ feat, float* __restrict__ res){
  __shared__ short As[128*32];
  __shared__ short Bs[64*32];
  int t = threadIdx.x;
  size_t i0 = (size_t)blockIdx.x*128;
  int w = t >> 6, l = t & 63, la = l & 15, lg = l >> 4;
  f32x4 acc[2][4];
  #pragma unroll
  for (int h=0;h<2;++h)
    #pragma unroll
    for (int c=0;c<4;++c) acc[h][c] = (f32x4){0.f,0.f,0.f,0.f};
  int ar0 = t >> 2;
  int ao0 = (t & 3) * 8;
  int ar1 = (t + 256) >> 2;
  for (int k0 = 0; k0 < DM; k0 += 32){
    gload16(attb + (i0 + ar0)*DM + k0 + ao0, &As[t*8]);
    gload16(attb + (i0 + ar1)*DM + k0 + ao0, &As[2048 + t*8]);
    gload16(W2t + (size_t)(t>>2)*DM + k0 + (t&3)*8, &Bs[t*8]);
    __syncthreads();
    s16x8 af[2], bg[4];
    #pragma unroll
    for (int h=0;h<2;++h) af[h] = *(const s16x8*)&As[(w*32 + h*16 + la)*32 + lg*8];
    #pragma unroll
    for (int c=0;c<4;++c) bg[c] = *(const s16x8*)&Bs[(c*16 + la)*32 + lg*8];
    #pragma unroll
    for (int h=0;h<2;++h)
      #pragma unroll
      for (int c=0;c<4;++c)
        acc[h][c] = __builtin_amdgcn_mfma_f32_16x16x32_bf16(af[h], bg[c], acc[h][c], 0, 0, 0);
    __syncthreads();
  }
  #pragma unroll
  for (int h=0;h<2;++h){
    #pragma unroll
    for (int c=0;c<4;++c){
      int col = c*16 + la;
      #pragma unroll
      for (int r=0;r<4;++r){
        size_t row = i0 + w*32 + h*16 + lg*4 + r;
        res[row*DP + col] = acc[h][c][r] + b2[col] + feat[row*DP + col];
      }
    }
  }
}

extern "C" void kernel_launch(void* const* d_in, const int* in_sizes, int n_in,
                              void* d_out, int out_size, void* d_ws, size_t ws_size,
                              hipStream_t stream){
  const float* xyz  = (const float*)d_in[0];
  const float* feat = (const float*)d_in[1];
  const float* W1   = (const float*)d_in[2];
  const float* b1   = (const float*)d_in[3];
  const float* W2   = (const float*)d_in[4];
  const float* b2   = (const float*)d_in[5];
  const float* Wd1  = (const float*)d_in[6];
  const float* bd1  = (const float*)d_in[7];
  const float* Wd2  = (const float*)d_in[8];
  const float* bd2  = (const float*)d_in[9];
  const float* Wq   = (const float*)d_in[10];
  const float* Wk   = (const float*)d_in[11];
  const float* Wv   = (const float*)d_in[12];

  char* ws = (char*)d_ws;                        // ~110 MB
  float* sq        = (float*)(ws + (0ull<<20));
  float* lsum_part = (float*)(ws + (1ull<<20));  // 2MB (reuses dead kidx/kw region after k_g)
  int*   kidx      = (int*)  (ws + (1ull<<20));
  float* kw        = (float*)(ws + (2ull<<20));
  float* wsum      = (float*)(ws + (3ull<<20));
  float* linv      = (float*)(ws + (3ull<<20));  // 64KB (reuses dead wsum after k_g)
  short* Wqt   = (short*)(ws + (4ull<<20));
  short* Wkt   = Wqt + (size_t)DM*DM;
  short* Wvt   = Wkt + (size_t)DM*DM;
  short* Wd2t  = Wvt + (size_t)DM*DM;
  short* W1t   = (short*)(ws + (6ull<<20));
  short* W2t   = (short*)(ws + (7ull<<20));
  short* featb = (short*)(ws + (8ull<<20));
  short* Prelu = (short*)(ws + (10ull<<20));     // reused as qe
  short* g     = (short*)(ws + (27ull<<20));     // reused as ke
  short* x     = (short*)(ws + (44ull<<20));     // reused as vt
  short* wab   = (short*)(ws + (61ull<<20));     // dead after QKV; pbuf lives at 61..93
  short* ve    = (short*)(ws + (78ull<<20));     // dead after k_vt
  short* pbuf  = (short*)(ws + (61ull<<20));     // 32MB bf16 P (half-width, per pass)
  short* attb  = (short*)(ws + (93ull<<20));     // 17MB (over dead ve tail)
  short* qe = Prelu; short* ke = g; short* vt = x;

  float* res  = (float*)d_out;
  float* attn = (float*)d_out + (size_t)ROWS*DP;

  k_sq   <<<ROWS/256, 256, 0, stream>>>(xyz, sq);
  k_knn  <<<ROWS/4, 256, 0, stream>>>(xyz, sq, kidx, kw, wsum);
  k_prep2<<<(4*DM*DM + 2*DM*DP + ROWS*DP)/256, 256, 0, stream>>>(
           Wq, Wk, Wv, Wd2, W1, W2, feat, Wqt, Wkt, Wvt, Wd2t, W1t, W2t, featb);
  k_prelu<<<(ROWS*DM)/256, 256, 0, stream>>>(xyz, Wd1, bd1, Prelu);
  k_g    <<<ROWS/4, 256, 0, stream>>>(Prelu, kidx, kw, wsum, g);
  k_gemm<DP,0>  <<<dim3(ROWS/128, DM/128), 256, 0, stream>>>(featb, W1t, b1, nullptr, x);
  k_gemm<DM,0>  <<<dim3(ROWS/128, DM/128), 256, 0, stream>>>(g, Wd2t, bd2, nullptr, wab);
  k_gemm<DM,1>  <<<dim3(ROWS/128, DM/128), 256, 0, stream>>>(x, Wqt, nullptr, wab, qe);
  k_gemm<DM,1>  <<<dim3(ROWS/128, DM/128), 256, 0, stream>>>(x, Wkt, nullptr, wab, ke);
  k_gemm<DM,1>  <<<dim3(ROWS/128, DM/128), 256, 0, stream>>>(x, Wvt, nullptr, wab, ve);
  k_vt   <<<dim3(NN/32, DM/32, BB), 256, 0, stream>>>(ve, vt);
  // attention as two GEMM passes over j-halves (pbuf reused between passes)
  k_sexp <<<1024, 256, 0, stream>>>(qe, ke, 0,    pbuf, lsum_part, 0);
  k_pv<0><<<512,  256, 0, stream>>>(pbuf, vt, 0,    linv, attn, attb);
  k_sexp <<<1024, 256, 0, stream>>>(qe, ke, 1024, pbuf, lsum_part, 8);
  k_lsum <<<ROWS/256, 256, 0, stream>>>(lsum_part, linv);
  k_pv<1><<<512,  256, 0, stream>>>(pbuf, vt, 1024, linv, attn, attb);
  k_res  <<<ROWS/128, 256, 0, stream>>>(attb, W2t, b2, feat, res);
}

// Round 7
// 335.095 us; speedup vs baseline: 2.2294x; 1.1393x over previous
//
#include <hip/hip_runtime.h>

#define BB 8
#define NN 2048
#define DP 64
#define DM 512
#define KNNK 16
#define ROWS (BB*NN)   // 16384

typedef __attribute__((ext_vector_type(8))) short s16x8;
typedef __attribute__((ext_vector_type(4))) short s16x4;
typedef __attribute__((ext_vector_type(4))) float f32x4;

__device__ __forceinline__ float bf2f(short u){
  union { unsigned int i; float f; } v; v.i = ((unsigned int)(unsigned short)u) << 16; return v.f;
}
__device__ __forceinline__ short f2bf(float f){
  union { float f; unsigned int i; } v; v.f = f;
  unsigned int x = v.i;
  return (short)((x + 0x7fffu + ((x >> 16) & 1u)) >> 16);
}

// global -> LDS direct (16B per lane)
__device__ __forceinline__ void gload16(const void* g, void* l){
  __builtin_amdgcn_global_load_lds(
      (const __attribute__((address_space(1))) void*)(__UINTPTR_TYPE__)g,
      (__attribute__((address_space(3))) void*)(__UINTPTR_TYPE__)l, 16, 0, 0);
}

// ---------------- sq = ||xyz||^2 ----------------
__global__ void k_sq(const float* __restrict__ xyz, float* __restrict__ sq){
  int i = blockIdx.x*256 + threadIdx.x;
  if (i < ROWS){
    float x = xyz[3*i], y = xyz[3*i+1], z = xyz[3*i+2];
    sq[i] = x*x + y*y + z*z;
  }
}

// ---------------- exact knn: wave-per-row, packed uint keys in 32 VGPRs ----------------
// key = (bits(max(d,0)) & ~2047) | j  (j = e*64 + lane, 11 bits). Unsigned order == float
// order for d>=0; ties within 11 low mantissa bits resolve to smaller j (stable-argsort-like).
// Per sel: 31 independent v_min_u32 + 6x(shfl+min) + SGPR-indexed invalidate.
__global__ __launch_bounds__(256) void k_knn(const float* __restrict__ xyz, const float* __restrict__ sq,
        int* __restrict__ kidx, float* __restrict__ kw, float* __restrict__ wsum){
  int row = blockIdx.x*4 + (threadIdx.x >> 6);
  int l = threadIdx.x & 63;
  int b = row >> 11; int i = row & (NN-1);
  const float* xb = xyz + (size_t)b*NN*3;
  const float* sqb = sq + (size_t)b*NN;
  float xi0 = xb[3*i], xi1 = xb[3*i+1], xi2 = xb[3*i+2];
  float sqi = sqb[i];
  unsigned key[32];
  #pragma unroll
  for (int e = 0; e < 32; ++e){
    int j = e*64 + l;
    float d = sqi + sqb[j] - 2.0f*(xi0*xb[3*j] + xi1*xb[3*j+1] + xi2*xb[3*j+2]);
    d = fmaxf(d, 0.f);
    union { float f; unsigned u; } cv; cv.f = d;
    key[e] = (cv.u & 0xFFFFF800u) | (unsigned)j;
  }
  float wacc = 0.f;
  for (int sel = 0; sel < KNNK; ++sel){
    unsigned kmin = key[0];
    #pragma unroll
    for (int e = 1; e < 32; ++e) kmin = min(kmin, key[e]);
    #pragma unroll
    for (int off = 32; off > 0; off >>= 1){
      unsigned o = __shfl_xor(kmin, off);
      kmin = min(kmin, o);
    }
    unsigned j = kmin & 2047u;
    union { unsigned u; float f; } dv; dv.u = kmin & 0xFFFFF800u;
    float wg = 1.0f/(dv.f + 1e-6f);
    wacc += wg;
    if (l == 0){
      kidx[(size_t)row*KNNK + sel] = (int)j;
      kw[(size_t)row*KNNK + sel] = wg;
    }
    int pe = __builtin_amdgcn_readfirstlane((int)(j >> 6));
    bool mine = (l == (int)(j & 63u));
    #pragma unroll
    for (int e = 0; e < 32; ++e)
      if (e == pe && mine) key[e] = 0xFFFFFFFFu;
  }
  if (l == 0) wsum[row] = wacc;
}

// ---------------- one-shot prep: transposed bf16 weights + featb ----------------
__global__ void k_prep2(const float* __restrict__ Wq, const float* __restrict__ Wk,
                        const float* __restrict__ Wv, const float* __restrict__ Wd2,
                        const float* __restrict__ W1, const float* __restrict__ W2,
                        const float* __restrict__ feat,
                        short* __restrict__ Wqt, short* __restrict__ Wkt,
                        short* __restrict__ Wvt, short* __restrict__ Wd2t,
                        short* __restrict__ W1t, short* __restrict__ W2t,
                        short* __restrict__ featb){
  int idx = blockIdx.x*256 + threadIdx.x;
  if (idx < 4*DM*DM){
    int m = idx >> 18;
    int r = idx & (DM*DM-1);
    int n = r >> 9, k = r & 511;
    const float* W = (m==0)?Wq:(m==1)?Wk:(m==2)?Wv:Wd2;
    short* Wt = (m==0)?Wqt:(m==1)?Wkt:(m==2)?Wvt:Wd2t;
    Wt[r] = f2bf(W[k*DM + n]);
  } else if (idx < 4*DM*DM + DM*DP){
    int r = idx - 4*DM*DM;
    int n = r >> 6, k = r & 63;
    W1t[r] = f2bf(W1[k*DM + n]);
  } else if (idx < 4*DM*DM + 2*DM*DP){
    int r = idx - 4*DM*DM - DM*DP;
    int n = r >> 9, k = r & 511;
    W2t[r] = f2bf(W2[k*DP + n]);
  } else {
    int r = idx - 4*DM*DM - 2*DM*DP;
    featb[r] = f2bf(feat[r]);
  }
}

// ---------------- Prelu[row][d] = relu(xyz@Wd1 + bd1), bf16 ----------------
__global__ void k_prelu(const float* __restrict__ xyz, const float* __restrict__ Wd1,
                        const float* __restrict__ bd1, short* __restrict__ Prelu){
  int idx = blockIdx.x*256 + threadIdx.x;
  int row = idx >> 9; int d = idx & (DM-1);
  float x0 = xyz[3*row], x1 = xyz[3*row+1], x2 = xyz[3*row+2];
  float v = x0*Wd1[d] + x1*Wd1[DM + d] + x2*Wd1[2*DM + d] + bd1[d];
  Prelu[idx] = f2bf(fmaxf(v, 0.f));
}

// ---------------- g = (sum_j w_j * Prelu[idx_j]) / wsum, bf16, batch-pinned ----------------
__global__ __launch_bounds__(256) void k_g(const short* __restrict__ Prelu, const int* __restrict__ kidx,
                   const float* __restrict__ kw, const float* __restrict__ wsum, short* __restrict__ g){
  int bid = blockIdx.x;
  int p = ((bid&7)<<11) + ((bid>>3)<<2) + (threadIdx.x>>6);   // batch = bid&7 (XCD-pinned)
  int c8 = (threadIdx.x&63)*8;
  int b = p >> 11;
  const short* Pb = Prelu + (size_t)b*NN*DM;
  int jj[KNNK]; float wj[KNNK];
  #pragma unroll
  for (int j = 0; j < KNNK; ++j){
    jj[j] = kidx[(size_t)p*KNNK + j];
    wj[j] = kw[(size_t)p*KNNK + j];
  }
  float acc[8] = {0,0,0,0,0,0,0,0};
  #pragma unroll
  for (int j = 0; j < KNNK; ++j){
    s16x8 v = *(const s16x8*)&Pb[(size_t)jj[j]*DM + c8];
    float w = wj[j];
    #pragma unroll
    for (int e=0;e<8;++e) acc[e] += w*bf2f(v[e]);
  }
  float inv = 1.0f/wsum[p];
  s16x8 o;
  #pragma unroll
  for (int e=0;e<8;++e) o[e] = f2bf(acc[e]*inv);
  *(s16x8*)&g[(size_t)p*DM + c8] = o;
}

// ---------------- bf16 MFMA GEMM template: C[M,512] = A[M,KD] @ Bt[512][KD]^T ----------------
template<int KD, int MODE>
__global__ __launch_bounds__(256) void k_gemm(const short* __restrict__ A, const short* __restrict__ Bt,
       const float* __restrict__ bias, const short* __restrict__ addb, short* __restrict__ outb){
  __shared__ short As[128*32];
  __shared__ short Bs[128*32];
  int t = threadIdx.x;
  size_t i0 = (size_t)blockIdx.x*128, n0 = (size_t)blockIdx.y*128;
  int w = t >> 6, l = t & 63, la = l & 15, lg = l >> 4;
  int wr = w >> 1, wc = w & 1;
  f32x4 acc[4][4];
  #pragma unroll
  for (int h=0;h<4;++h)
    #pragma unroll
    for (int c=0;c<4;++c) acc[h][c] = (f32x4){0.f,0.f,0.f,0.f};
  int srow = t >> 2; int sk8 = (t & 3) * 8;
  const short* Ab  = A  + (i0 + srow)*KD + sk8;
  const short* Ab2 = A  + (i0 + 64 + srow)*KD + sk8;
  const short* Bb  = Bt + (n0 + srow)*KD + sk8;
  const short* Bb2 = Bt + (n0 + 64 + srow)*KD + sk8;
  short* Asd  = &As[t*8];      short* Asd2 = &As[2048 + t*8];
  short* Bsd  = &Bs[t*8];      short* Bsd2 = &Bs[2048 + t*8];
  for (int k0 = 0; k0 < KD; k0 += 32){
    gload16(Ab  + k0, Asd);
    gload16(Ab2 + k0, Asd2);
    gload16(Bb  + k0, Bsd);
    gload16(Bb2 + k0, Bsd2);
    __syncthreads();
    s16x8 af[4], bg[4];
    #pragma unroll
    for (int h=0;h<4;++h) af[h] = *(const s16x8*)&As[(wr*64 + h*16 + la)*32 + lg*8];
    #pragma unroll
    for (int c=0;c<4;++c) bg[c] = *(const s16x8*)&Bs[(wc*64 + c*16 + la)*32 + lg*8];
    #pragma unroll
    for (int h=0;h<4;++h)
      #pragma unroll
      for (int c=0;c<4;++c)
        acc[h][c] = __builtin_amdgcn_mfma_f32_16x16x32_bf16(af[h], bg[c], acc[h][c], 0, 0, 0);
    __syncthreads();
  }
  #pragma unroll
  for (int h=0;h<4;++h){
    #pragma unroll
    for (int c=0;c<4;++c){
      size_t col = n0 + wc*64 + c*16 + la;
      #pragma unroll
      for (int r=0;r<4;++r){
        size_t row = i0 + wr*64 + h*16 + lg*4 + r;
        float v = acc[h][c][r];
        if (MODE == 0) outb[row*DM + col] = f2bf(v + bias[col]);
        else           outb[row*DM + col] = f2bf(v + bf2f(addb[row*DM + col]));
      }
    }
  }
}

// ---------------- transpose ve -> vt[b][d][j] ----------------
__global__ __launch_bounds__(256) void k_vt(const short* __restrict__ ve, short* __restrict__ vt){
  int j0 = blockIdx.x*32, d0 = blockIdx.y*32, b = blockIdx.z;
  __shared__ short tile[32][36];
  int t = threadIdx.x;
  int r = t >> 3, c4 = (t & 7)*4;
  const short* vb = ve + (size_t)b*NN*DM;
  *(s16x4*)&tile[r][c4] = *(const s16x4*)&vb[(size_t)(j0+r)*DM + d0 + c4];
  __syncthreads();
  s16x4 o;
  #pragma unroll
  for (int e=0;e<4;++e) o[e] = tile[c4+e][r];
  short* ob = vt + (size_t)b*DM*NN;
  *(s16x4*)&ob[(size_t)(d0+r)*NN + j0 + c4] = o;
}

// ---------------- S-GEMM + exp: P[b][i][jlocal] = exp(scale * qe_i . ke_(joff+j)) ----------------
__global__ __launch_bounds__(256) void k_sexp(const short* __restrict__ qe, const short* __restrict__ ke,
       int joff, short* __restrict__ pbuf, float* __restrict__ lsum_part, int slot0){
  __shared__ short As[128*32];
  __shared__ short Bs[128*32];
  int bid = blockIdx.x;
  int b = bid & 7;
  int r2 = bid >> 3;                 // 0..127
  int ti = r2 & 15, tj = r2 >> 4;    // i-tile 0..15, j-tile 0..7
  size_t i0 = (size_t)ti*128;
  size_t j0 = (size_t)tj*128;        // local to this pass
  const short* A  = qe + (size_t)b*NN*DM;
  const short* Bt = ke + (size_t)b*NN*DM + (size_t)joff*DM;
  int t = threadIdx.x;
  int w = t >> 6, l = t & 63, la = l & 15, lg = l >> 4;
  int wr = w >> 1, wc = w & 1;
  f32x4 acc[4][4];
  #pragma unroll
  for (int h=0;h<4;++h)
    #pragma unroll
    for (int c=0;c<4;++c) acc[h][c] = (f32x4){0.f,0.f,0.f,0.f};
  int srow = t >> 2; int sk8 = (t & 3) * 8;
  const short* Ab  = A  + (i0 + srow)*DM + sk8;
  const short* Ab2 = A  + (i0 + 64 + srow)*DM + sk8;
  const short* Bb  = Bt + (j0 + srow)*DM + sk8;
  const short* Bb2 = Bt + (j0 + 64 + srow)*DM + sk8;
  short* Asd  = &As[t*8];      short* Asd2 = &As[2048 + t*8];
  short* Bsd  = &Bs[t*8];      short* Bsd2 = &Bs[2048 + t*8];
  for (int k0 = 0; k0 < DM; k0 += 32){
    gload16(Ab  + k0, Asd);
    gload16(Ab2 + k0, Asd2);
    gload16(Bb  + k0, Bsd);
    gload16(Bb2 + k0, Bsd2);
    __syncthreads();
    s16x8 af[4], bg[4];
    #pragma unroll
    for (int h=0;h<4;++h) af[h] = *(const s16x8*)&As[(wr*64 + h*16 + la)*32 + lg*8];
    #pragma unroll
    for (int c=0;c<4;++c) bg[c] = *(const s16x8*)&Bs[(wc*64 + c*16 + la)*32 + lg*8];
    #pragma unroll
    for (int h=0;h<4;++h)
      #pragma unroll
      for (int c=0;c<4;++c)
        acc[h][c] = __builtin_amdgcn_mfma_f32_16x16x32_bf16(af[h], bg[c], acc[h][c], 0, 0, 0);
    __syncthreads();
  }
  const float scale = 0.044194173824159216f;  // 1/sqrt(512)
  short* pb = pbuf + (size_t)b*NN*1024;
  float rsum[4][4];
  #pragma unroll
  for (int h=0;h<4;++h)
    #pragma unroll
    for (int r=0;r<4;++r) rsum[h][r] = 0.f;
  #pragma unroll
  for (int h=0;h<4;++h){
    #pragma unroll
    for (int c=0;c<4;++c){
      size_t col = j0 + wc*64 + c*16 + la;
      #pragma unroll
      for (int r=0;r<4;++r){
        size_t row = i0 + wr*64 + h*16 + lg*4 + r;
        float p = __expf(acc[h][c][r]*scale);
        rsum[h][r] += p;
        pb[row*1024 + col] = f2bf(p);
      }
    }
  }
  #pragma unroll
  for (int m = 1; m < 16; m <<= 1){
    #pragma unroll
    for (int h=0;h<4;++h)
      #pragma unroll
      for (int r=0;r<4;++r) rsum[h][r] += __shfl_xor(rsum[h][r], m);
  }
  if (la == 0){
    float* lp = lsum_part + (size_t)((slot0 + tj)*2 + wc)*ROWS + (size_t)b*NN;
    #pragma unroll
    for (int h=0;h<4;++h)
      #pragma unroll
      for (int r=0;r<4;++r)
        lp[i0 + wr*64 + h*16 + lg*4 + r] = rsum[h][r];
  }
}

// ---------------- linv = 1 / sum over 32 partial slots ----------------
__global__ void k_lsum(const float* __restrict__ lsum_part, float* __restrict__ linv){
  int g = blockIdx.x*256 + threadIdx.x;
  float s = 0.f;
  #pragma unroll
  for (int i = 0; i < 32; ++i) s += lsum_part[(size_t)i*ROWS + g];
  linv[g] = 1.0f/s;
}

// ---------------- PV GEMM: O = P @ V (vt is [b][d][j]) ----------------
template<int FINAL>
__global__ __launch_bounds__(256) void k_pv(const short* __restrict__ pbuf, const short* __restrict__ vt,
        int joff, const float* __restrict__ linv, float* __restrict__ attn, short* __restrict__ attb){
  __shared__ short As[128*32];
  __shared__ short Bs[128*32];
  int bid = blockIdx.x;
  int b = bid & 7;
  int r2 = bid >> 3;                 // 0..63
  int ti = r2 & 15, tn = r2 >> 4;    // i-tile 0..15, d-tile 0..3
  size_t i0 = (size_t)ti*128;
  size_t n0 = (size_t)tn*128;
  const short* A  = pbuf + (size_t)b*NN*1024;
  const short* Bt = vt + (size_t)b*DM*NN + joff;
  int t = threadIdx.x;
  int w = t >> 6, l = t & 63, la = l & 15, lg = l >> 4;
  int wr = w >> 1, wc = w & 1;
  f32x4 acc[4][4];
  #pragma unroll
  for (int h=0;h<4;++h)
    #pragma unroll
    for (int c=0;c<4;++c) acc[h][c] = (f32x4){0.f,0.f,0.f,0.f};
  int srow = t >> 2; int sk8 = (t & 3) * 8;
  const short* Ab  = A  + (i0 + srow)*1024 + sk8;
  const short* Ab2 = A  + (i0 + 64 + srow)*1024 + sk8;
  const short* Bb  = Bt + (n0 + srow)*NN + sk8;
  const short* Bb2 = Bt + (n0 + 64 + srow)*NN + sk8;
  short* Asd  = &As[t*8];      short* Asd2 = &As[2048 + t*8];
  short* Bsd  = &Bs[t*8];      short* Bsd2 = &Bs[2048 + t*8];
  for (int k0 = 0; k0 < 1024; k0 += 32){
    gload16(Ab  + k0, Asd);
    gload16(Ab2 + k0, Asd2);
    gload16(Bb  + k0, Bsd);
    gload16(Bb2 + k0, Bsd2);
    __syncthreads();
    s16x8 af[4], bg[4];
    #pragma unroll
    for (int h=0;h<4;++h) af[h] = *(const s16x8*)&As[(wr*64 + h*16 + la)*32 + lg*8];
    #pragma unroll
    for (int c=0;c<4;++c) bg[c] = *(const s16x8*)&Bs[(wc*64 + c*16 + la)*32 + lg*8];
    #pragma unroll
    for (int h=0;h<4;++h)
      #pragma unroll
      for (int c=0;c<4;++c)
        acc[h][c] = __builtin_amdgcn_mfma_f32_16x16x32_bf16(af[h], bg[c], acc[h][c], 0, 0, 0);
    __syncthreads();
  }
  #pragma unroll
  for (int h=0;h<4;++h){
    #pragma unroll
    for (int c=0;c<4;++c){
      size_t col = n0 + wc*64 + c*16 + la;
      #pragma unroll
      for (int r=0;r<4;++r){
        size_t row = i0 + wr*64 + h*16 + lg*4 + r;
        size_t off = (size_t)b*NN*DM + row*DM + col;
        if (FINAL == 0){
          attn[off] = acc[h][c][r];
        } else {
          float v = (attn[off] + acc[h][c][r]) * linv[(size_t)b*NN + row];
          attn[off] = v;
          attb[off] = f2bf(v);
        }
      }
    }
  }
}

// ---------------- res = attb@W2t^T + b2 + feat (MFMA, N=64) ----------------
__global__ __launch_bounds__(256) void k_res(const short* __restrict__ attb, const short* __restrict__ W2t,
       const float* __restrict__ b2, const float* __restrict__ feat, float* __restrict__ res){
  __shared__ short As[128*32];
  __shared__ short Bs[64*32];
  int t = threadIdx.x;
  size_t i0 = (size_t)blockIdx.x*128;
  int w = t >> 6, l = t & 63, la = l & 15, lg = l >> 4;
  f32x4 acc[2][4];
  #pragma unroll
  for (int h=0;h<2;++h)
    #pragma unroll
    for (int c=0;c<4;++c) acc[h][c] = (f32x4){0.f,0.f,0.f,0.f};
  int ar0 = t >> 2;
  int ao0 = (t & 3) * 8;
  int ar1 = (t + 256) >> 2;
  for (int k0 = 0; k0 < DM; k0 += 32){
    gload16(attb + (i0 + ar0)*DM + k0 + ao0, &As[t*8]);
    gload16(attb + (i0 + ar1)*DM + k0 + ao0, &As[2048 + t*8]);
    gload16(W2t + (size_t)(t>>2)*DM + k0 + (t&3)*8, &Bs[t*8]);
    __syncthreads();
    s16x8 af[2], bg[4];
    #pragma unroll
    for (int h=0;h<2;++h) af[h] = *(const s16x8*)&As[(w*32 + h*16 + la)*32 + lg*8];
    #pragma unroll
    for (int c=0;c<4;++c) bg[c] = *(const s16x8*)&Bs[(c*16 + la)*32 + lg*8];
    #pragma unroll
    for (int h=0;h<2;++h)
      #pragma unroll
      for (int c=0;c<4;++c)
        acc[h][c] = __builtin_amdgcn_mfma_f32_16x16x32_bf16(af[h], bg[c], acc[h][c], 0, 0, 0);
    __syncthreads();
  }
  #pragma unroll
  for (int h=0;h<2;++h){
    #pragma unroll
    for (int c=0;c<4;++c){
      int col = c*16 + la;
      #pragma unroll
      for (int r=0;r<4;++r){
        size_t row = i0 + w*32 + h*16 + lg*4 + r;
        res[row*DP + col] = acc[h][c][r] + b2[col] + feat[row*DP + col];
      }
    }
  }
}

extern "C" void kernel_launch(void* const* d_in, const int* in_sizes, int n_in,
                              void* d_out, int out_size, void* d_ws, size_t ws_size,
                              hipStream_t stream){
  const float* xyz  = (const float*)d_in[0];
  const float* feat = (const float*)d_in[1];
  const float* W1   = (const float*)d_in[2];
  const float* b1   = (const float*)d_in[3];
  const float* W2   = (const float*)d_in[4];
  const float* b2   = (const float*)d_in[5];
  const float* Wd1  = (const float*)d_in[6];
  const float* bd1  = (const float*)d_in[7];
  const float* Wd2  = (const float*)d_in[8];
  const float* bd2  = (const float*)d_in[9];
  const float* Wq   = (const float*)d_in[10];
  const float* Wk   = (const float*)d_in[11];
  const float* Wv   = (const float*)d_in[12];

  char* ws = (char*)d_ws;                        // ~110 MB
  float* sq        = (float*)(ws + (0ull<<20));
  float* lsum_part = (float*)(ws + (1ull<<20));  // 2MB (reuses dead kidx/kw region after k_g)
  int*   kidx      = (int*)  (ws + (1ull<<20));
  float* kw        = (float*)(ws + (2ull<<20));
  float* wsum      = (float*)(ws + (3ull<<20));
  float* linv      = (float*)(ws + (3ull<<20));  // 64KB (reuses dead wsum after k_g)
  short* Wqt   = (short*)(ws + (4ull<<20));
  short* Wkt   = Wqt + (size_t)DM*DM;
  short* Wvt   = Wkt + (size_t)DM*DM;
  short* Wd2t  = Wvt + (size_t)DM*DM;
  short* W1t   = (short*)(ws + (6ull<<20));
  short* W2t   = (short*)(ws + (7ull<<20));
  short* featb = (short*)(ws + (8ull<<20));
  short* Prelu = (short*)(ws + (10ull<<20));     // reused as qe
  short* g     = (short*)(ws + (27ull<<20));     // reused as ke
  short* x     = (short*)(ws + (44ull<<20));     // reused as vt
  short* wab   = (short*)(ws + (61ull<<20));     // dead after QKV; pbuf lives at 61..93
  short* ve    = (short*)(ws + (78ull<<20));     // dead after k_vt
  short* pbuf  = (short*)(ws + (61ull<<20));     // 32MB bf16 P (half-width, per pass)
  short* attb  = (short*)(ws + (93ull<<20));     // 17MB (over dead ve tail)
  short* qe = Prelu; short* ke = g; short* vt = x;

  float* res  = (float*)d_out;
  float* attn = (float*)d_out + (size_t)ROWS*DP;

  k_sq   <<<ROWS/256, 256, 0, stream>>>(xyz, sq);
  k_knn  <<<ROWS/4, 256, 0, stream>>>(xyz, sq, kidx, kw, wsum);
  k_prep2<<<(4*DM*DM + 2*DM*DP + ROWS*DP)/256, 256, 0, stream>>>(
           Wq, Wk, Wv, Wd2, W1, W2, feat, Wqt, Wkt, Wvt, Wd2t, W1t, W2t, featb);
  k_prelu<<<(ROWS*DM)/256, 256, 0, stream>>>(xyz, Wd1, bd1, Prelu);
  k_g    <<<ROWS/4, 256, 0, stream>>>(Prelu, kidx, kw, wsum, g);
  k_gemm<DP,0>  <<<dim3(ROWS/128, DM/128), 256, 0, stream>>>(featb, W1t, b1, nullptr, x);
  k_gemm<DM,0>  <<<dim3(ROWS/128, DM/128), 256, 0, stream>>>(g, Wd2t, bd2, nullptr, wab);
  k_gemm<DM,1>  <<<dim3(ROWS/128, DM/128), 256, 0, stream>>>(x, Wqt, nullptr, wab, qe);
  k_gemm<DM,1>  <<<dim3(ROWS/128, DM/128), 256, 0, stream>>>(x, Wkt, nullptr, wab, ke);
  k_gemm<DM,1>  <<<dim3(ROWS/128, DM/128), 256, 0, stream>>>(x, Wvt, nullptr, wab, ve);
  k_vt   <<<dim3(NN/32, DM/32, BB), 256, 0, stream>>>(ve, vt);
  // attention as two GEMM passes over j-halves (pbuf reused between passes)
  k_sexp <<<1024, 256, 0, stream>>>(qe, ke, 0,    pbuf, lsum_part, 0);
  k_pv<0><<<512,  256, 0, stream>>>(pbuf, vt, 0,    linv, attn, attb);
  k_sexp <<<1024, 256, 0, stream>>>(qe, ke, 1024, pbuf, lsum_part, 8);
  k_lsum <<<ROWS/256, 256, 0, stream>>>(lsum_part, linv);
  k_pv<1><<<512,  256, 0, stream>>>(pbuf, vt, 1024, linv, attn, attb);
  k_res  <<<ROWS/128, 256, 0, stream>>>(attb, W2t, b2, feat, res);
}